// Round 1
// baseline (2130.274 us; speedup 1.0000x reference)
//
#include <hip/hip_runtime.h>
#include <hip/hip_bf16.h>
#include <math.h>

#define LN_EPS 1e-5f
#define NEGS 0.2f

// ---- helpers ---------------------------------------------------------------

// monotone float<->uint encoding for atomicMax-based float max (0 == "-inf")
__device__ __forceinline__ unsigned int fenc(float x) {
    unsigned int u = __float_as_uint(x);
    return (u & 0x80000000u) ? ~u : (u | 0x80000000u);
}
__device__ __forceinline__ float fdec(unsigned int u) {
    unsigned int v = (u & 0x80000000u) ? (u & 0x7fffffffu) : ~u;
    return __uint_as_float(v);
}
__device__ __forceinline__ float wredsum(float v) {
#pragma unroll
    for (int s = 32; s > 0; s >>= 1) v += __shfl_xor(v, s);
    return v;
}

// ---- K1: incoming-edge count + edge-attr sum per dst -----------------------
__global__ void k_count_sum(const float* __restrict__ rel, const int* __restrict__ dst,
                            float* __restrict__ lsum, float* __restrict__ cnt, int E) {
    long long idx = (long long)blockIdx.x * blockDim.x + threadIdx.x;
    long long tot = (long long)E * 64;
    long long stride = (long long)gridDim.x * blockDim.x;
    for (; idx < tot; idx += stride) {
        int e = (int)(idx >> 6);
        int c = (int)(idx & 63);
        int d = dst[e];
        atomicAdd(&lsum[(long long)d * 64 + c], rel[idx]);
        if (c == 0) atomicAdd(&cnt[d], 1.0f);
    }
}

// ---- K2: y = x @ W + b   (N x 64) @ (64 x 320) -----------------------------
__global__ __launch_bounds__(512) void k_lin(const float* __restrict__ x,
                                             const float* __restrict__ W,
                                             const float* __restrict__ b,
                                             float* __restrict__ y, int N) {
    __shared__ float w[64 * 320];  // 80 KB
    int t = threadIdx.x;
    for (int i = t; i < 64 * 320; i += 512) w[i] = W[i];
    __syncthreads();
    int wv = t >> 6, ln = t & 63;
    for (long long base = (long long)blockIdx.x * 8; base < N; base += (long long)gridDim.x * 8) {
        long long node = base + wv;
        bool ok = node < N;
        long long nn = ok ? node : (long long)(N - 1);
        float xv = x[nn * 64 + ln];
        float acc[5];
#pragma unroll
        for (int q = 0; q < 5; q++) acc[q] = b[q * 64 + ln];
        for (int k = 0; k < 64; k++) {
            float xk = __shfl(xv, k);
#pragma unroll
            for (int q = 0; q < 5; q++) acc[q] = fmaf(xk, w[k * 320 + q * 64 + ln], acc[q]);
        }
        if (ok) {
#pragma unroll
            for (int q = 0; q < 5; q++) y[nn * 320 + q * 64 + ln] = acc[q];
        }
    }
}

// ---- K3: self-loop logits --------------------------------------------------
__global__ __launch_bounds__(512) void k_self(const float* __restrict__ lsum,
                                              const float* __restrict__ cnt,
                                              const float* __restrict__ Weg,
                                              const float* __restrict__ attg,
                                              const float* __restrict__ xl,
                                              const float* __restrict__ xr,
                                              float* __restrict__ logitsS,
                                              unsigned int* __restrict__ mx, int N) {
    __shared__ float w[64 * 320];  // 80 KB
    int t = threadIdx.x;
    for (int i = t; i < 64 * 320; i += 512) w[i] = Weg[i];
    __syncthreads();
    int wv = t >> 6, ln = t & 63;
    for (long long base = (long long)blockIdx.x * 8; base < N; base += (long long)gridDim.x * 8) {
        long long node = base + wv;
        bool ok = node < N;
        long long nn = ok ? node : (long long)(N - 1);
        float c = cnt[nn];
        float inv = 1.0f / fmaxf(c, 1.0f);
        float la = lsum[nn * 64 + ln] * inv;
        float acc[5];
#pragma unroll
        for (int q = 0; q < 5; q++) acc[q] = 0.f;
        for (int k = 0; k < 64; k++) {
            float lk = __shfl(la, k);
#pragma unroll
            for (int q = 0; q < 5; q++) acc[q] = fmaf(lk, w[k * 320 + q * 64 + ln], acc[q]);
        }
#pragma unroll
        for (int q = 0; q < 5; q++) {
            float v = xl[nn * 320 + q * 64 + ln] + xr[nn * 320 + q * 64 + ln] + acc[q];
            v = v > 0.f ? v : v * NEGS;
            float r = wredsum(v * attg[q * 64 + ln]);
            if (ok && ln == q) {
                logitsS[nn * 5 + q] = r;
                atomicMax(&mx[nn * 5 + q], fenc(r));
            }
        }
    }
}

// ---- K4: edge logits (em = rel @ We on the fly) ----------------------------
__global__ __launch_bounds__(512) void k_edge(const float* __restrict__ rel,
                                              const int* __restrict__ src,
                                              const int* __restrict__ dst,
                                              const float* __restrict__ xl,
                                              const float* __restrict__ xr,
                                              const float* __restrict__ Weg,
                                              const float* __restrict__ attg,
                                              float* __restrict__ logits,
                                              unsigned int* __restrict__ mx, int E) {
    __shared__ float w[64 * 320];  // 80 KB -> 2 blocks/CU, 16 waves/CU
    int t = threadIdx.x;
    for (int i = t; i < 64 * 320; i += 512) w[i] = Weg[i];
    __syncthreads();
    int wv = t >> 6, ln = t & 63;
    long long wid = (long long)blockIdx.x * 8 + wv;
    long long nw = (long long)gridDim.x * 8;
    float attv[5];
#pragma unroll
    for (int q = 0; q < 5; q++) attv[q] = attg[q * 64 + ln];
    for (long long g = wid * 8; g < E; g += nw * 8) {
        int ne = (int)(((long long)E - g) < 8 ? ((long long)E - g) : 8);
        int sj[8], dj[8];
        float rv[8];
#pragma unroll
        for (int j = 0; j < 8; j++) {
            long long e = g + (j < ne ? j : 0);
            sj[j] = src[e];
            dj[j] = dst[e];
            rv[j] = rel[e * 64 + ln];
        }
        float acc[8][5];
#pragma unroll
        for (int j = 0; j < 8; j++)
#pragma unroll
            for (int q = 0; q < 5; q++) acc[j][q] = 0.f;
        for (int k = 0; k < 64; k++) {
            float wk[5];
#pragma unroll
            for (int q = 0; q < 5; q++) wk[q] = w[k * 320 + q * 64 + ln];
#pragma unroll
            for (int j = 0; j < 8; j++) {
                float rk = __shfl(rv[j], k);
#pragma unroll
                for (int q = 0; q < 5; q++) acc[j][q] = fmaf(rk, wk[q], acc[j][q]);
            }
        }
#pragma unroll
        for (int j = 0; j < 8; j++) {
            if (j < ne) {
                long long e = g + j;
                long long so = (long long)sj[j] * 320, dofs = (long long)dj[j] * 320;
#pragma unroll
                for (int q = 0; q < 5; q++) {
                    float v = xl[so + q * 64 + ln] + xr[dofs + q * 64 + ln] + acc[j][q];
                    v = v > 0.f ? v : v * NEGS;
                    float r = wredsum(v * attv[q]);
                    if (ln == q) {
                        logits[e * 5 + q] = r;
                        atomicMax(&mx[(long long)dj[j] * 5 + q], fenc(r));
                    }
                }
            }
        }
    }
}

// ---- K5: z = exp(logit - max), denominator ---------------------------------
__global__ void k_z(float* __restrict__ logits, float* __restrict__ logitsS,
                    const int* __restrict__ dst, const unsigned int* __restrict__ mx,
                    float* __restrict__ den, int E, int N) {
    long long idx = (long long)blockIdx.x * blockDim.x + threadIdx.x;
    long long tot = (long long)(E + N) * 5;
    long long stride = (long long)gridDim.x * blockDim.x;
    for (; idx < tot; idx += stride) {
        long long i = idx / 5;
        int h = (int)(idx - i * 5);
        int d;
        float* p;
        if (i < E) {
            d = dst[i];
            p = &logits[idx];
        } else {
            d = (int)(i - E);
            p = &logitsS[(long long)d * 5 + h];
        }
        float lg = *p;
        float m = fdec(mx[(long long)d * 5 + h]);
        float z = expf(lg - m);
        *p = z;
        atomicAdd(&den[(long long)d * 5 + h], z);
    }
}

// ---- K6: conv[dst,c] += sum_h alpha_h * xl[src,h,c] / H --------------------
__global__ void k_accum(const float* __restrict__ z, const float* __restrict__ zS,
                        const float* __restrict__ den, const int* __restrict__ src,
                        const int* __restrict__ dst, const float* __restrict__ xl,
                        float* __restrict__ conv, int E, int N) {
    long long idx = (long long)blockIdx.x * blockDim.x + threadIdx.x;
    long long tot = (long long)(E + N) * 64;
    long long stride = (long long)gridDim.x * blockDim.x;
    for (; idx < tot; idx += stride) {
        long long i = idx >> 6;
        int c = (int)(idx & 63);
        int s, d;
        const float* zp;
        if (i < E) {
            s = src[i];
            d = dst[i];
            zp = &z[i * 5];
        } else {
            s = d = (int)(i - E);
            zp = &zS[(long long)s * 5];
        }
        float a = 0.f;
#pragma unroll
        for (int h = 0; h < 5; h++) {
            float al = zp[h] / den[(long long)d * 5 + h];
            a = fmaf(al, xl[(long long)s * 320 + h * 64 + c], a);
        }
        atomicAdd(&conv[(long long)d * 64 + c], a * 0.2f);
    }
}

// ---- K7: residual + LN -> MLP(64->128->64) -> residual + LN ----------------
__global__ __launch_bounds__(512) void k_mlp(const float* __restrict__ feat,
                                             const float* __restrict__ conv,
                                             const float* __restrict__ cbias,
                                             const float* __restrict__ lng,
                                             const float* __restrict__ lnb,
                                             const float* __restrict__ ln1g,
                                             const float* __restrict__ ln1b,
                                             const float* __restrict__ fcwg,
                                             const float* __restrict__ fcb,
                                             const float* __restrict__ fc1wg,
                                             const float* __restrict__ fc1b,
                                             float* __restrict__ out, int N) {
    __shared__ float w1[64 * 128];  // 32 KB
    __shared__ float w2[128 * 64];  // 32 KB
    __shared__ float xs[8][64];
    __shared__ float ts[8][128];
    int t = threadIdx.x;
    for (int i = t; i < 64 * 128; i += 512) w1[i] = fcwg[i];
    for (int i = t; i < 128 * 64; i += 512) w2[i] = fc1wg[i];
    __syncthreads();
    int wv = t >> 6, ln = t & 63;
    for (long long base = (long long)blockIdx.x * 8; base < N; base += (long long)gridDim.x * 8) {
        long long node = base + wv;
        bool ok = node < N;
        long long nn = ok ? node : (long long)(N - 1);
        float xv = feat[nn * 64 + ln] + conv[nn * 64 + ln] + cbias[ln];
        float mu = wredsum(xv) * (1.0f / 64.0f);
        float dv = xv - mu;
        float var = wredsum(dv * dv) * (1.0f / 64.0f);
        float xn = dv * rsqrtf(var + LN_EPS) * lng[ln] + lnb[ln];
        xs[wv][ln] = xn;
        __syncthreads();
        float t0 = fcb[ln], t1 = fcb[64 + ln];
        for (int k = 0; k < 64; k++) {
            float xk = xs[wv][k];
            t0 = fmaf(xk, w1[k * 128 + ln], t0);
            t1 = fmaf(xk, w1[k * 128 + 64 + ln], t1);
        }
        ts[wv][ln] = t0;
        ts[wv][64 + ln] = t1;
        __syncthreads();
        float h = fc1b[ln];
        for (int j = 0; j < 128; j++) {
            h = fmaf(ts[wv][j], w2[j * 64 + ln], h);
        }
        float y = xn + h;
        float mu2 = wredsum(y) * (1.0f / 64.0f);
        float dv2 = y - mu2;
        float var2 = wredsum(dv2 * dv2) * (1.0f / 64.0f);
        float o = dv2 * rsqrtf(var2 + LN_EPS) * ln1g[ln] + ln1b[ln];
        if (ok) out[nn * 64 + ln] = o;
        __syncthreads();
    }
}

// ---- launch ----------------------------------------------------------------
extern "C" void kernel_launch(void* const* d_in, const int* in_sizes, int n_in,
                              void* d_out, int out_size, void* d_ws, size_t ws_size,
                              hipStream_t stream) {
    const float* feat = (const float*)d_in[0];
    const int* ei = (const int*)d_in[1];
    const float* rel = (const float*)d_in[2];
    const float* Wl = (const float*)d_in[3];
    const float* bl = (const float*)d_in[4];
    const float* Wr = (const float*)d_in[5];
    const float* br = (const float*)d_in[6];
    const float* We = (const float*)d_in[7];
    const float* att = (const float*)d_in[8];
    const float* cbias = (const float*)d_in[9];
    const float* lng = (const float*)d_in[10];
    const float* lnb = (const float*)d_in[11];
    const float* ln1g = (const float*)d_in[12];
    const float* ln1b = (const float*)d_in[13];
    const float* fcw = (const float*)d_in[14];
    const float* fcb = (const float*)d_in[15];
    const float* fc1w = (const float*)d_in[16];
    const float* fc1b = (const float*)d_in[17];
    float* out = (float*)d_out;

    int N = in_sizes[0] / 64;
    int E = in_sizes[1] / 2;
    const int* src = ei;
    const int* dst = ei + E;

    float* ws = (float*)d_ws;
    float* xl = ws;               ws += (size_t)N * 320;
    float* xr = ws;               ws += (size_t)N * 320;
    float* lsum = ws;             ws += (size_t)N * 64;
    float* cnt = ws;              ws += (size_t)N;
    float* conv = ws;             ws += (size_t)N * 64;
    float* logits = ws;           ws += (size_t)E * 5;
    float* logitsS = ws;          ws += (size_t)N * 5;
    unsigned int* mx = (unsigned int*)ws;  ws += (size_t)N * 5;
    float* den = ws;              ws += (size_t)N * 5;

    hipMemsetAsync(lsum, 0, (size_t)N * 64 * 4, stream);
    hipMemsetAsync(cnt, 0, (size_t)N * 4, stream);
    hipMemsetAsync(conv, 0, (size_t)N * 64 * 4, stream);
    hipMemsetAsync(mx, 0, (size_t)N * 5 * 4, stream);
    hipMemsetAsync(den, 0, (size_t)N * 5 * 4, stream);

    k_count_sum<<<4096, 256, 0, stream>>>(rel, dst, lsum, cnt, E);
    k_lin<<<768, 512, 0, stream>>>(feat, Wl, bl, xl, N);
    k_lin<<<768, 512, 0, stream>>>(feat, Wr, br, xr, N);
    k_self<<<768, 512, 0, stream>>>(lsum, cnt, We, att, xl, xr, logitsS, mx, N);
    k_edge<<<2048, 512, 0, stream>>>(rel, src, dst, xl, xr, We, att, logits, mx, E);
    k_z<<<4096, 256, 0, stream>>>(logits, logitsS, dst, mx, den, E, N);
    k_accum<<<8192, 256, 0, stream>>>(logits, logitsS, den, src, dst, xl, conv, E, N);
    k_mlp<<<512, 512, 0, stream>>>(feat, conv, cbias, lng, lnb, ln1g, ln1b, fcw, fcb, fc1w, fc1b,
                                   out, N);
}

// Round 2
// 1419.485 us; speedup vs baseline: 1.5007x; 1.5007x over previous
//
#include <hip/hip_runtime.h>
#include <hip/hip_bf16.h>
#include <math.h>

#define LN_EPS 1e-5f
#define NEGS 0.2f

typedef short s8v __attribute__((ext_vector_type(8)));
typedef float f4v __attribute__((ext_vector_type(4)));

// ---- helpers ---------------------------------------------------------------

// monotone float<->uint encoding for atomicMax-based float max (0 == "-inf")
__device__ __forceinline__ unsigned int fenc(float x) {
    unsigned int u = __float_as_uint(x);
    return (u & 0x80000000u) ? ~u : (u | 0x80000000u);
}
__device__ __forceinline__ float fdec(unsigned int u) {
    unsigned int v = (u & 0x80000000u) ? (u & 0x7fffffffu) : ~u;
    return __uint_as_float(v);
}
__device__ __forceinline__ float wredsum(float v) {
#pragma unroll
    for (int s = 32; s > 0; s >>= 1) v += __shfl_xor(v, s);
    return v;
}
// fp32 -> bf16 round-to-nearest-even
__device__ __forceinline__ unsigned short f2bf(float x) {
    unsigned int u = __float_as_uint(x);
    u += 0x7fffu + ((u >> 16) & 1u);
    return (unsigned short)(u >> 16);
}

// ---- K1: incoming-edge count + edge-attr sum per dst -----------------------
__global__ void k_count_sum(const float* __restrict__ rel, const int* __restrict__ dst,
                            float* __restrict__ lsum, float* __restrict__ cnt, int E) {
    long long idx = (long long)blockIdx.x * blockDim.x + threadIdx.x;
    long long tot = (long long)E * 64;
    long long stride = (long long)gridDim.x * blockDim.x;
    for (; idx < tot; idx += stride) {
        int e = (int)(idx >> 6);
        int c = (int)(idx & 63);
        int d = dst[e];
        atomicAdd(&lsum[(long long)d * 64 + c], rel[idx]);
        if (c == 0) atomicAdd(&cnt[d], 1.0f);
    }
}

// ---- K1b: loop_attr = lsum / max(cnt,1) ------------------------------------
__global__ void k_loopattr(const float* __restrict__ lsum, const float* __restrict__ cnt,
                           float* __restrict__ loopat, int N) {
    int idx = blockIdx.x * blockDim.x + threadIdx.x;
    int tot = N * 64;
    int stride = gridDim.x * blockDim.x;
    for (; idx < tot; idx += stride) {
        int n = idx >> 6;
        loopat[idx] = lsum[idx] / fmaxf(cnt[n], 1.0f);
    }
}

// ---- K2: y = x @ W + b   (N x 64) @ (64 x 320) -----------------------------
__global__ __launch_bounds__(512) void k_lin(const float* __restrict__ x,
                                             const float* __restrict__ W,
                                             const float* __restrict__ b,
                                             float* __restrict__ y, int N) {
    __shared__ float w[64 * 320];  // 80 KB
    int t = threadIdx.x;
    for (int i = t; i < 64 * 320; i += 512) w[i] = W[i];
    __syncthreads();
    int wv = t >> 6, ln = t & 63;
    for (long long base = (long long)blockIdx.x * 8; base < N; base += (long long)gridDim.x * 8) {
        long long node = base + wv;
        bool ok = node < N;
        long long nn = ok ? node : (long long)(N - 1);
        float xv = x[nn * 64 + ln];
        float acc[5];
#pragma unroll
        for (int q = 0; q < 5; q++) acc[q] = b[q * 64 + ln];
        for (int k = 0; k < 64; k++) {
            float xk = __shfl(xv, k);
#pragma unroll
            for (int q = 0; q < 5; q++) acc[q] = fmaf(xk, w[k * 320 + q * 64 + ln], acc[q]);
        }
        if (ok) {
#pragma unroll
            for (int q = 0; q < 5; q++) y[nn * 320 + q * 64 + ln] = acc[q];
        }
    }
}

// ---- K3: fused em-MFMA + logits for ALL rows (edges + self loops) ----------
// Row i < E: ea = rel[i], s = src[i], d = dst[i].
// Row i in [E, M): ea = loop_attr[i-E], s = d = i-E.
// logits[i*5+h] = sum_c leaky(xl[s,h,c] + xr[d,h,c] + (ea @ We)[h,c]) * att[h,c]
__global__ __launch_bounds__(256) void k_fused(
    const float* __restrict__ rel, const float* __restrict__ loopat,
    const int* __restrict__ src, const int* __restrict__ dst,
    const float* __restrict__ xl, const float* __restrict__ xr,
    const float* __restrict__ Weg, const float* __restrict__ attg,
    float* __restrict__ logits, unsigned int* __restrict__ mx,
    int E, int M) {
    // We^T in LDS, bf16, layout [n][k]: byte = n*128 + k*2, XOR-swizzled.
    __shared__ __align__(16) unsigned short weT[64 * 320];  // 40 KB
    int t = threadIdx.x;
    for (int idx = t; idx < 64 * 320; idx += 256) {
        int k = idx / 320;
        int n = idx - k * 320;          // coalesced read of We[k][n]
        int byte = n * 128 + k * 2;
        byte ^= (n & 7) << 4;           // bank-conflict swizzle (bits 4-6)
        weT[byte >> 1] = f2bf(Weg[idx]);
    }
    __syncthreads();

    int l = t & 63, wv = t >> 6;
    int g = l >> 4, m = l & 15;         // g: k-chunk / row-subgroup, m: tile row / col
    int r0 = (blockIdx.x * 4 + wv) * 64;
    if (r0 >= M) return;                // no further barriers below

    // per-lane att values: att[h*64 + ct*16 + m]
    float attv[5][4];
#pragma unroll
    for (int h = 0; h < 5; h++)
#pragma unroll
        for (int ct = 0; ct < 4; ct++) attv[h][ct] = attg[h * 64 + ct * 16 + m];

    // A fragments: lane holds ea[row = r0+rt*16+m][k = kh*32 + g*8 + j], bf16
    s8v afr[4][2];
#pragma unroll
    for (int rt = 0; rt < 4; rt++) {
        int row = r0 + rt * 16 + m;
        if (row >= M) row = M - 1;
        const float* ap = (row < E) ? (rel + (long long)row * 64)
                                    : (loopat + (long long)(row - E) * 64);
#pragma unroll
        for (int kh = 0; kh < 2; kh++) {
            const float* p = ap + kh * 32 + g * 8;
            float4 u0 = *(const float4*)(p);
            float4 u1 = *(const float4*)(p + 4);
            s8v a;
            a[0] = (short)f2bf(u0.x); a[1] = (short)f2bf(u0.y);
            a[2] = (short)f2bf(u0.z); a[3] = (short)f2bf(u0.w);
            a[4] = (short)f2bf(u1.x); a[5] = (short)f2bf(u1.y);
            a[6] = (short)f2bf(u1.z); a[7] = (short)f2bf(u1.w);
            afr[rt][kh] = a;
        }
    }

#pragma unroll
    for (int h = 0; h < 5; h++) {
        f4v acc[4][4];  // [ct][rt]
#pragma unroll
        for (int ct = 0; ct < 4; ct++)
#pragma unroll
            for (int rt = 0; rt < 4; rt++) acc[ct][rt] = (f4v)0.0f;

#pragma unroll
        for (int ct = 0; ct < 4; ct++) {
            int n = h * 64 + ct * 16 + m;
            int b0 = (n * 128 + 0 * 64 + g * 16) ^ ((n & 7) << 4);
            int b1 = (n * 128 + 1 * 64 + g * 16) ^ ((n & 7) << 4);
            s8v bf0 = *(const s8v*)((const char*)weT + b0);
            s8v bf1 = *(const s8v*)((const char*)weT + b1);
#pragma unroll
            for (int rt = 0; rt < 4; rt++) {
                acc[ct][rt] = __builtin_amdgcn_mfma_f32_16x16x32_bf16(afr[rt][0], bf0, acc[ct][rt], 0, 0, 0);
                acc[ct][rt] = __builtin_amdgcn_mfma_f32_16x16x32_bf16(afr[rt][1], bf1, acc[ct][rt], 0, 0, 0);
            }
        }

        // epilogue: D[row=g*4+q (in tile rt), col=m (in tile ct)]
#pragma unroll
        for (int rt = 0; rt < 4; rt++) {
#pragma unroll
            for (int q = 0; q < 4; q++) {
                int row = r0 + rt * 16 + g * 4 + q;
                bool ok = row < M;
                int rr = ok ? row : (M - 1);
                int s, d;
                if (rr < E) { s = src[rr]; d = dst[rr]; }
                else        { s = d = rr - E; }
                float sum = 0.f;
#pragma unroll
                for (int ct = 0; ct < 4; ct++) {
                    int col = h * 64 + ct * 16 + m;
                    float v = acc[ct][rt][q] + xl[(long long)s * 320 + col]
                                             + xr[(long long)d * 320 + col];
                    v = v > 0.f ? v : v * NEGS;
                    sum = fmaf(v, attv[h][ct], sum);
                }
                sum += __shfl_xor(sum, 1);
                sum += __shfl_xor(sum, 2);
                sum += __shfl_xor(sum, 4);
                sum += __shfl_xor(sum, 8);
                if (ok && m == 0) {
                    logits[(long long)rr * 5 + h] = sum;
                    atomicMax(&mx[(long long)d * 5 + h], fenc(sum));
                }
            }
        }
    }
}

// ---- K5: z = exp(logit - max), denominator ---------------------------------
__global__ void k_z(float* __restrict__ logits, const int* __restrict__ dst,
                    const unsigned int* __restrict__ mx, float* __restrict__ den,
                    int E, int M) {
    long long idx = (long long)blockIdx.x * blockDim.x + threadIdx.x;
    long long tot = (long long)M * 5;
    long long stride = (long long)gridDim.x * blockDim.x;
    for (; idx < tot; idx += stride) {
        int i = (int)(idx / 5);
        int h = (int)(idx - (long long)i * 5);
        int d = (i < E) ? dst[i] : (i - E);
        float lg = logits[idx];
        float z = expf(lg - fdec(mx[(long long)d * 5 + h]));
        logits[idx] = z;
        atomicAdd(&den[(long long)d * 5 + h], z);
    }
}

// ---- K6: conv[dst,c] += sum_h alpha_h * xl[src,h,c] / H --------------------
__global__ void k_accum(const float* __restrict__ z, const float* __restrict__ den,
                        const int* __restrict__ src, const int* __restrict__ dst,
                        const float* __restrict__ xl, float* __restrict__ conv,
                        int E, int M) {
    long long idx = (long long)blockIdx.x * blockDim.x + threadIdx.x;
    long long tot = (long long)M * 64;
    long long stride = (long long)gridDim.x * blockDim.x;
    for (; idx < tot; idx += stride) {
        int i = (int)(idx >> 6);
        int c = (int)(idx & 63);
        int s, d;
        if (i < E) { s = src[i]; d = dst[i]; }
        else       { s = d = i - E; }
        const float* zp = &z[(long long)i * 5];
        float a = 0.f;
#pragma unroll
        for (int h = 0; h < 5; h++) {
            float al = zp[h] / den[(long long)d * 5 + h];
            a = fmaf(al, xl[(long long)s * 320 + h * 64 + c], a);
        }
        atomicAdd(&conv[(long long)d * 64 + c], a * 0.2f);
    }
}

// ---- K7: residual + LN -> MLP(64->128->64) -> residual + LN ----------------
__global__ __launch_bounds__(512) void k_mlp(const float* __restrict__ feat,
                                             const float* __restrict__ conv,
                                             const float* __restrict__ cbias,
                                             const float* __restrict__ lng,
                                             const float* __restrict__ lnb,
                                             const float* __restrict__ ln1g,
                                             const float* __restrict__ ln1b,
                                             const float* __restrict__ fcwg,
                                             const float* __restrict__ fcb,
                                             const float* __restrict__ fc1wg,
                                             const float* __restrict__ fc1b,
                                             float* __restrict__ out, int N) {
    __shared__ float w1[64 * 128];  // 32 KB
    __shared__ float w2[128 * 64];  // 32 KB
    __shared__ float xs[8][64];
    __shared__ float ts[8][128];
    int t = threadIdx.x;
    for (int i = t; i < 64 * 128; i += 512) w1[i] = fcwg[i];
    for (int i = t; i < 128 * 64; i += 512) w2[i] = fc1wg[i];
    __syncthreads();
    int wv = t >> 6, ln = t & 63;
    for (long long base = (long long)blockIdx.x * 8; base < N; base += (long long)gridDim.x * 8) {
        long long node = base + wv;
        bool ok = node < N;
        long long nn = ok ? node : (long long)(N - 1);
        float xv = feat[nn * 64 + ln] + conv[nn * 64 + ln] + cbias[ln];
        float mu = wredsum(xv) * (1.0f / 64.0f);
        float dv = xv - mu;
        float var = wredsum(dv * dv) * (1.0f / 64.0f);
        float xn = dv * rsqrtf(var + LN_EPS) * lng[ln] + lnb[ln];
        xs[wv][ln] = xn;
        __syncthreads();
        float t0 = fcb[ln], t1 = fcb[64 + ln];
        for (int k = 0; k < 64; k++) {
            float xk = xs[wv][k];
            t0 = fmaf(xk, w1[k * 128 + ln], t0);
            t1 = fmaf(xk, w1[k * 128 + 64 + ln], t1);
        }
        ts[wv][ln] = t0;
        ts[wv][64 + ln] = t1;
        __syncthreads();
        float h = fc1b[ln];
        for (int j = 0; j < 128; j++) {
            h = fmaf(ts[wv][j], w2[j * 64 + ln], h);
        }
        float y = xn + h;
        float mu2 = wredsum(y) * (1.0f / 64.0f);
        float dv2 = y - mu2;
        float var2 = wredsum(dv2 * dv2) * (1.0f / 64.0f);
        float o = dv2 * rsqrtf(var2 + LN_EPS) * ln1g[ln] + ln1b[ln];
        if (ok) out[nn * 64 + ln] = o;
        __syncthreads();
    }
}

// ---- launch ----------------------------------------------------------------
extern "C" void kernel_launch(void* const* d_in, const int* in_sizes, int n_in,
                              void* d_out, int out_size, void* d_ws, size_t ws_size,
                              hipStream_t stream) {
    const float* feat = (const float*)d_in[0];
    const int* ei = (const int*)d_in[1];
    const float* rel = (const float*)d_in[2];
    const float* Wl = (const float*)d_in[3];
    const float* bl = (const float*)d_in[4];
    const float* Wr = (const float*)d_in[5];
    const float* br = (const float*)d_in[6];
    const float* We = (const float*)d_in[7];
    const float* att = (const float*)d_in[8];
    const float* cbias = (const float*)d_in[9];
    const float* lng = (const float*)d_in[10];
    const float* lnb = (const float*)d_in[11];
    const float* ln1g = (const float*)d_in[12];
    const float* ln1b = (const float*)d_in[13];
    const float* fcw = (const float*)d_in[14];
    const float* fcb = (const float*)d_in[15];
    const float* fc1w = (const float*)d_in[16];
    const float* fc1b = (const float*)d_in[17];
    float* out = (float*)d_out;

    int N = in_sizes[0] / 64;
    int E = in_sizes[1] / 2;
    int M = E + N;
    const int* src = ei;
    const int* dst = ei + E;

    float* ws = (float*)d_ws;
    float* xl = ws;               ws += (size_t)N * 320;
    float* xr = ws;               ws += (size_t)N * 320;
    float* lsum = ws;             ws += (size_t)N * 64;
    float* cnt = ws;              ws += (size_t)N;
    float* conv = ws;             ws += (size_t)N * 64;
    float* loopat = ws;           ws += (size_t)N * 64;
    float* logits = ws;           ws += (size_t)M * 5;
    unsigned int* mx = (unsigned int*)ws;  ws += (size_t)N * 5;
    float* den = ws;              ws += (size_t)N * 5;

    hipMemsetAsync(lsum, 0, (size_t)N * 64 * 4, stream);
    hipMemsetAsync(cnt, 0, (size_t)N * 4, stream);
    hipMemsetAsync(conv, 0, (size_t)N * 64 * 4, stream);
    hipMemsetAsync(mx, 0, (size_t)N * 5 * 4, stream);
    hipMemsetAsync(den, 0, (size_t)N * 5 * 4, stream);

    k_count_sum<<<4096, 256, 0, stream>>>(rel, dst, lsum, cnt, E);
    k_loopattr<<<4096, 256, 0, stream>>>(lsum, cnt, loopat, N);
    k_lin<<<768, 512, 0, stream>>>(feat, Wl, bl, xl, N);
    k_lin<<<768, 512, 0, stream>>>(feat, Wr, br, xr, N);
    k_fused<<<(M + 255) / 256, 256, 0, stream>>>(rel, loopat, src, dst, xl, xr, We, att,
                                                 logits, mx, E, M);
    k_z<<<4096, 256, 0, stream>>>(logits, dst, mx, den, E, M);
    k_accum<<<8192, 256, 0, stream>>>(logits, den, src, dst, xl, conv, E, M);
    k_mlp<<<512, 512, 0, stream>>>(feat, conv, cbias, lng, lnb, ln1g, ln1b, fcw, fcb, fc1w, fc1b,
                                   out, N);
}

// Round 3
// 1062.497 us; speedup vs baseline: 2.0050x; 1.3360x over previous
//
#include <hip/hip_runtime.h>
#include <hip/hip_bf16.h>
#include <math.h>

#define LN_EPS 1e-5f
#define NEGS 0.2f

typedef short s8v __attribute__((ext_vector_type(8)));
typedef float f4v __attribute__((ext_vector_type(4)));
typedef unsigned short ushort;

// ---- helpers ---------------------------------------------------------------
__device__ __forceinline__ float wredsum(float v) {
#pragma unroll
    for (int s = 32; s > 0; s >>= 1) v += __shfl_xor(v, s);
    return v;
}
// fp32 -> bf16 round-to-nearest-even
__device__ __forceinline__ ushort f2bf(float x) {
    unsigned int u = __float_as_uint(x);
    u += 0x7fffu + ((u >> 16) & 1u);
    return (ushort)(u >> 16);
}
__device__ __forceinline__ float bf2f(ushort u) {
    return __uint_as_float(((unsigned int)u) << 16);
}

// ---- K0: histogram of dst --------------------------------------------------
__global__ void k_hist(const int* __restrict__ dst, int* __restrict__ cnt, int E) {
    int idx = blockIdx.x * blockDim.x + threadIdx.x;
    int stride = gridDim.x * blockDim.x;
    for (; idx < E; idx += stride) atomicAdd(&cnt[dst[idx]], 1);
}

// ---- K0b: single-block exclusive scan of (cnt[i]+1) ------------------------
// roff[n] = sum_{i<n}(cnt[i]+1); roff[N] = E+N. wpos seeded = roff.
__global__ __launch_bounds__(1024) void k_scan(const int* __restrict__ cnt,
                                               int* __restrict__ roff,
                                               int* __restrict__ wpos, int N) {
    __shared__ int wsum[16];
    __shared__ int carry_s;
    int t = threadIdx.x;
    int ln = t & 63, wv = t >> 6;
    if (t == 0) carry_s = 0;
    __syncthreads();
    for (int base = 0; base < N; base += 1024) {
        int i = base + t;
        int v = (i < N) ? (cnt[i] + 1) : 0;
        int x = v;  // inclusive wave scan
#pragma unroll
        for (int off = 1; off < 64; off <<= 1) {
            int y = __shfl_up(x, off);
            if (ln >= off) x += y;
        }
        if (ln == 63) wsum[wv] = x;
        __syncthreads();
        if (wv == 0) {
            int wsv = (ln < 16) ? wsum[ln] : 0;
            int xs = wsv;
#pragma unroll
            for (int off = 1; off < 16; off <<= 1) {
                int y = __shfl_up(xs, off);
                if (ln >= off) xs += y;
            }
            if (ln < 16) wsum[ln] = xs - wsv;  // exclusive wave offsets
        }
        __syncthreads();
        int excl = x - v + wsum[wv] + carry_s;
        if (i < N) { roff[i] = excl; wpos[i] = excl; }
        __syncthreads();
        if (t == 1023) carry_s += x + wsum[15];
        __syncthreads();
    }
    if (t == 0) roff[N] = carry_s;
}

// ---- K0c: scatter edges into CSR slots ------------------------------------
__global__ void k_scatter(const int* __restrict__ src, const int* __restrict__ dst,
                          int* __restrict__ wpos, int* __restrict__ eidC,
                          int* __restrict__ srcC, int* __restrict__ posC, int E) {
    int idx = blockIdx.x * blockDim.x + threadIdx.x;
    int stride = gridDim.x * blockDim.x;
    for (; idx < E; idx += stride) {
        int d = dst[idx];
        int p = atomicAdd(&wpos[d], 1);
        eidC[p] = idx;
        srcC[p] = src[idx];
        posC[idx] = p;
    }
}

// ---- K1: per-node loop_attr (mean of incident rel) via CSR; no atomics -----
__global__ __launch_bounds__(256) void k_loopcsr(const int* __restrict__ eidC,
                                                 const int* __restrict__ roff,
                                                 const float* __restrict__ rel,
                                                 float* __restrict__ loopat,
                                                 int* __restrict__ srcC, int N) {
    int t = threadIdx.x, ln = t & 63, wv = t >> 6;
    int nw = gridDim.x * 4;
    for (int n = blockIdx.x * 4 + wv; n < N; n += nw) {
        int r0 = roff[n], r1 = roff[n + 1];
        int deg = r1 - r0 - 1;  // real edges (last slot = self)
        float s = 0.f;
        for (int j = 0; j < deg; j++) {
            int e = eidC[r0 + j];
            s += rel[(long long)e * 64 + ln];
        }
        loopat[(long long)n * 64 + ln] = s / (float)(deg > 0 ? deg : 1);
        if (ln == 0) srcC[r1 - 1] = n;  // self-loop source
    }
}

// ---- K2: y = bf16(x @ W + b)   (N x 64) @ (64 x 320) -----------------------
__global__ __launch_bounds__(512) void k_lin(const float* __restrict__ x,
                                             const float* __restrict__ W,
                                             const float* __restrict__ b,
                                             ushort* __restrict__ y, int N) {
    __shared__ float w[64 * 320];  // 80 KB
    int t = threadIdx.x;
    for (int i = t; i < 64 * 320; i += 512) w[i] = W[i];
    __syncthreads();
    int wv = t >> 6, ln = t & 63;
    for (long long base = (long long)blockIdx.x * 8; base < N; base += (long long)gridDim.x * 8) {
        long long node = base + wv;
        bool ok = node < N;
        long long nn = ok ? node : (long long)(N - 1);
        float xv = x[nn * 64 + ln];
        float acc[5];
#pragma unroll
        for (int q = 0; q < 5; q++) acc[q] = b[q * 64 + ln];
        for (int k = 0; k < 64; k++) {
            float xk = __shfl(xv, k);
#pragma unroll
            for (int q = 0; q < 5; q++) acc[q] = fmaf(xk, w[k * 320 + q * 64 + ln], acc[q]);
        }
        if (ok) {
#pragma unroll
            for (int q = 0; q < 5; q++) y[nn * 320 + q * 64 + ln] = f2bf(acc[q]);
        }
    }
}

// ---- K3: fused em-MFMA + logits for ALL rows (edges + self loops) ----------
// Row i < E: ea = rel[i], s=src[i], d=dst[i], slot = posC[i].
// Row i in [E,M): ea = loop_attr[i-E], s=d=i-E, slot = roff[i-E+1]-1.
__global__ __launch_bounds__(512) void k_fused(
    const float* __restrict__ rel, const float* __restrict__ loopat,
    const int* __restrict__ src, const int* __restrict__ dst,
    const ushort* __restrict__ xlbf, const ushort* __restrict__ xrbf,
    const float* __restrict__ Weg, const float* __restrict__ attg,
    const int* __restrict__ posC, const int* __restrict__ roff,
    float* __restrict__ logitsC, int E, int M) {
    // We^T in LDS, bf16, layout [n][k]: byte = n*128 + k*2, XOR-swizzled.
    __shared__ __align__(16) ushort weT[64 * 320];  // 40 KB
    int t = threadIdx.x;
    for (int idx = t; idx < 64 * 320; idx += 512) {
        int k = idx / 320;
        int n = idx - k * 320;
        int byte = n * 128 + k * 2;
        byte ^= (n & 7) << 4;
        weT[byte >> 1] = f2bf(Weg[idx]);
    }
    __syncthreads();

    int l = t & 63, wv = t >> 6;
    int g = l >> 4, m = l & 15;
    int r0 = (blockIdx.x * 8 + wv) * 32;
    if (r0 >= M) return;

    // A fragments: lane holds ea[row = r0+rt*16+m][k = kh*32 + g*8 + j]
    s8v afr[2][2];
#pragma unroll
    for (int rt = 0; rt < 2; rt++) {
        int row = r0 + rt * 16 + m;
        if (row >= M) row = M - 1;
        const float* ap = (row < E) ? (rel + (long long)row * 64)
                                    : (loopat + (long long)(row - E) * 64);
#pragma unroll
        for (int kh = 0; kh < 2; kh++) {
            const float* p = ap + kh * 32 + g * 8;
            float4 u0 = *(const float4*)(p);
            float4 u1 = *(const float4*)(p + 4);
            s8v a;
            a[0] = (short)f2bf(u0.x); a[1] = (short)f2bf(u0.y);
            a[2] = (short)f2bf(u0.z); a[3] = (short)f2bf(u0.w);
            a[4] = (short)f2bf(u1.x); a[5] = (short)f2bf(u1.y);
            a[6] = (short)f2bf(u1.z); a[7] = (short)f2bf(u1.w);
            afr[rt][kh] = a;
        }
    }

    // hoist src/dst for the 8 epilogue rows of this lane's g-group
    int sarr[2][4], darr[2][4];
#pragma unroll
    for (int rt = 0; rt < 2; rt++)
#pragma unroll
        for (int q = 0; q < 4; q++) {
            int row = r0 + rt * 16 + g * 4 + q;
            int rr = row < M ? row : M - 1;
            int s, d;
            if (rr < E) { s = src[rr]; d = dst[rr]; }
            else        { s = d = rr - E; }
            sarr[rt][q] = s; darr[rt][q] = d;
        }

#pragma unroll
    for (int h = 0; h < 5; h++) {
        f4v acc[4][2];  // [ct][rt]
#pragma unroll
        for (int ct = 0; ct < 4; ct++)
#pragma unroll
            for (int rt = 0; rt < 2; rt++) acc[ct][rt] = (f4v)0.0f;

#pragma unroll
        for (int ct = 0; ct < 4; ct++) {
            int n = h * 64 + ct * 16 + m;
            int b0 = (n * 128 + 0 * 64 + g * 16) ^ ((n & 7) << 4);
            int b1 = (n * 128 + 1 * 64 + g * 16) ^ ((n & 7) << 4);
            s8v bf0 = *(const s8v*)((const char*)weT + b0);
            s8v bf1 = *(const s8v*)((const char*)weT + b1);
#pragma unroll
            for (int rt = 0; rt < 2; rt++) {
                acc[ct][rt] = __builtin_amdgcn_mfma_f32_16x16x32_bf16(afr[rt][0], bf0, acc[ct][rt], 0, 0, 0);
                acc[ct][rt] = __builtin_amdgcn_mfma_f32_16x16x32_bf16(afr[rt][1], bf1, acc[ct][rt], 0, 0, 0);
            }
        }

        float attv[4];
#pragma unroll
        for (int ct = 0; ct < 4; ct++) attv[ct] = attg[h * 64 + ct * 16 + m];

#pragma unroll
        for (int rt = 0; rt < 2; rt++) {
#pragma unroll
            for (int q = 0; q < 4; q++) {
                const ushort* xp = xlbf + (long long)sarr[rt][q] * 320 + h * 64 + m;
                const ushort* rp = xrbf + (long long)darr[rt][q] * 320 + h * 64 + m;
                float sum = 0.f;
#pragma unroll
                for (int ct = 0; ct < 4; ct++) {
                    float v = acc[ct][rt][q] + bf2f(xp[ct * 16]) + bf2f(rp[ct * 16]);
                    v = v > 0.f ? v : v * NEGS;
                    sum = fmaf(v, attv[ct], sum);
                }
                sum += __shfl_xor(sum, 1);
                sum += __shfl_xor(sum, 2);
                sum += __shfl_xor(sum, 4);
                sum += __shfl_xor(sum, 8);
                int row = r0 + rt * 16 + g * 4 + q;
                if (row < M && m == 0) {
                    int p = (row < E) ? posC[row] : (roff[row - E + 1] - 1);
                    logitsC[(long long)p * 5 + h] = sum;
                }
            }
        }
    }
}

// ---- K4: per-node softmax + conv accumulation (no atomics) -----------------
__global__ __launch_bounds__(256) void k_agg(const float* __restrict__ logitsC,
                                             const int* __restrict__ srcC,
                                             const int* __restrict__ roff,
                                             const ushort* __restrict__ xlbf,
                                             float* __restrict__ conv, int N) {
    int t = threadIdx.x, ln = t & 63, wv = t >> 6;
    int nw = gridDim.x * 4;
    for (int n = blockIdx.x * 4 + wv; n < N; n += nw) {
        int r0 = roff[n], r1 = roff[n + 1];
        int deg = r1 - r0;  // includes self slot
        float mh[5], dh[5];
#pragma unroll
        for (int h = 0; h < 5; h++) {
            float m = -3.4e38f;
            for (int j = ln; j < deg; j += 64)
                m = fmaxf(m, logitsC[(long long)(r0 + j) * 5 + h]);
#pragma unroll
            for (int s = 32; s > 0; s >>= 1) m = fmaxf(m, __shfl_xor(m, s));
            float sden = 0.f;
            for (int j = ln; j < deg; j += 64)
                sden += expf(logitsC[(long long)(r0 + j) * 5 + h] - m);
            sden = wredsum(sden);
            mh[h] = m;
            dh[h] = 1.0f / sden;
        }
        float acc = 0.f;
        for (int j = 0; j < deg; j++) {
            int slot = r0 + j;
            int s = srcC[slot];
            const ushort* xp = xlbf + (long long)s * 320 + ln;
#pragma unroll
            for (int h = 0; h < 5; h++) {
                float a = expf(logitsC[(long long)slot * 5 + h] - mh[h]) * dh[h];
                acc = fmaf(a, bf2f(xp[h * 64]), acc);
            }
        }
        conv[(long long)n * 64 + ln] = acc * 0.2f;
    }
}

// ---- K5: residual + LN -> MLP(64->128->64) -> residual + LN ----------------
__global__ __launch_bounds__(512) void k_mlp(const float* __restrict__ feat,
                                             const float* __restrict__ conv,
                                             const float* __restrict__ cbias,
                                             const float* __restrict__ lng,
                                             const float* __restrict__ lnb,
                                             const float* __restrict__ ln1g,
                                             const float* __restrict__ ln1b,
                                             const float* __restrict__ fcwg,
                                             const float* __restrict__ fcb,
                                             const float* __restrict__ fc1wg,
                                             const float* __restrict__ fc1b,
                                             float* __restrict__ out, int N) {
    __shared__ float w1[64 * 128];
    __shared__ float w2[128 * 64];
    __shared__ float xs[8][64];
    __shared__ float ts[8][128];
    int t = threadIdx.x;
    for (int i = t; i < 64 * 128; i += 512) w1[i] = fcwg[i];
    for (int i = t; i < 128 * 64; i += 512) w2[i] = fc1wg[i];
    __syncthreads();
    int wv = t >> 6, ln = t & 63;
    for (long long base = (long long)blockIdx.x * 8; base < N; base += (long long)gridDim.x * 8) {
        long long node = base + wv;
        bool ok = node < N;
        long long nn = ok ? node : (long long)(N - 1);
        float xv = feat[nn * 64 + ln] + conv[nn * 64 + ln] + cbias[ln];
        float mu = wredsum(xv) * (1.0f / 64.0f);
        float dv = xv - mu;
        float var = wredsum(dv * dv) * (1.0f / 64.0f);
        float xn = dv * rsqrtf(var + LN_EPS) * lng[ln] + lnb[ln];
        xs[wv][ln] = xn;
        __syncthreads();
        float t0 = fcb[ln], t1 = fcb[64 + ln];
        for (int k = 0; k < 64; k++) {
            float xk = xs[wv][k];
            t0 = fmaf(xk, w1[k * 128 + ln], t0);
            t1 = fmaf(xk, w1[k * 128 + 64 + ln], t1);
        }
        ts[wv][ln] = t0;
        ts[wv][64 + ln] = t1;
        __syncthreads();
        float h = fc1b[ln];
        for (int j = 0; j < 128; j++) {
            h = fmaf(ts[wv][j], w2[j * 64 + ln], h);
        }
        float y = xn + h;
        float mu2 = wredsum(y) * (1.0f / 64.0f);
        float dv2 = y - mu2;
        float var2 = wredsum(dv2 * dv2) * (1.0f / 64.0f);
        float o = dv2 * rsqrtf(var2 + LN_EPS) * ln1g[ln] + ln1b[ln];
        if (ok) out[nn * 64 + ln] = o;
        __syncthreads();
    }
}

// ---- launch ----------------------------------------------------------------
extern "C" void kernel_launch(void* const* d_in, const int* in_sizes, int n_in,
                              void* d_out, int out_size, void* d_ws, size_t ws_size,
                              hipStream_t stream) {
    const float* feat = (const float*)d_in[0];
    const int* ei = (const int*)d_in[1];
    const float* rel = (const float*)d_in[2];
    const float* Wl = (const float*)d_in[3];
    const float* bl = (const float*)d_in[4];
    const float* Wr = (const float*)d_in[5];
    const float* br = (const float*)d_in[6];
    const float* We = (const float*)d_in[7];
    const float* att = (const float*)d_in[8];
    const float* cbias = (const float*)d_in[9];
    const float* lng = (const float*)d_in[10];
    const float* lnb = (const float*)d_in[11];
    const float* ln1g = (const float*)d_in[12];
    const float* ln1b = (const float*)d_in[13];
    const float* fcw = (const float*)d_in[14];
    const float* fcb = (const float*)d_in[15];
    const float* fc1w = (const float*)d_in[16];
    const float* fc1b = (const float*)d_in[17];
    float* out = (float*)d_out;

    int N = in_sizes[0] / 64;
    int E = in_sizes[1] / 2;
    int M = E + N;
    const int* src = ei;
    const int* dst = ei + E;

    char* wsb = (char*)d_ws;
    ushort* xlbf = (ushort*)wsb;            wsb += (size_t)N * 320 * 2;
    ushort* xrbf = (ushort*)wsb;            wsb += (size_t)N * 320 * 2;
    float* loopat = (float*)wsb;            wsb += (size_t)N * 64 * 4;
    float* conv = (float*)wsb;              wsb += (size_t)N * 64 * 4;
    float* logitsC = (float*)wsb;           wsb += (size_t)M * 5 * 4;
    int* cnt = (int*)wsb;                   wsb += (size_t)N * 4;
    int* roff = (int*)wsb;                  wsb += (size_t)(N + 1) * 4;
    int* wpos = (int*)wsb;                  wsb += (size_t)N * 4;
    int* eidC = (int*)wsb;                  wsb += (size_t)M * 4;
    int* srcC = (int*)wsb;                  wsb += (size_t)M * 4;
    int* posC = (int*)wsb;                  wsb += (size_t)E * 4;

    hipMemsetAsync(cnt, 0, (size_t)N * 4, stream);

    k_hist<<<1024, 256, 0, stream>>>(dst, cnt, E);
    k_scan<<<1, 1024, 0, stream>>>(cnt, roff, wpos, N);
    k_scatter<<<1024, 256, 0, stream>>>(src, dst, wpos, eidC, srcC, posC, E);
    k_loopcsr<<<2048, 256, 0, stream>>>(eidC, roff, rel, loopat, srcC, N);
    k_lin<<<768, 512, 0, stream>>>(feat, Wl, bl, xlbf, N);
    k_lin<<<768, 512, 0, stream>>>(feat, Wr, br, xrbf, N);
    k_fused<<<(M + 255) / 256, 512, 0, stream>>>(rel, loopat, src, dst, xlbf, xrbf, We, att,
                                                 posC, roff, logitsC, E, M);
    k_agg<<<2048, 256, 0, stream>>>(logitsC, srcC, roff, xlbf, conv, N);
    k_mlp<<<512, 512, 0, stream>>>(feat, conv, cbias, lng, lnb, ln1g, ln1b, fcw, fcb, fc1w, fc1b,
                                   out, N);
}

// Round 4
// 923.561 us; speedup vs baseline: 2.3066x; 1.1504x over previous
//
#include <hip/hip_runtime.h>
#include <hip/hip_bf16.h>
#include <math.h>

#define LN_EPS 1e-5f
#define NEGS 0.2f

typedef short s8v __attribute__((ext_vector_type(8)));
typedef short s4v __attribute__((ext_vector_type(4)));
typedef float f4v __attribute__((ext_vector_type(4)));
typedef unsigned short ushort;

// ---- helpers ---------------------------------------------------------------
__device__ __forceinline__ float wredsum(float v) {
#pragma unroll
    for (int s = 32; s > 0; s >>= 1) v += __shfl_xor(v, s);
    return v;
}
// fp32 -> bf16 round-to-nearest-even
__device__ __forceinline__ ushort f2bf(float x) {
    unsigned int u = __float_as_uint(x);
    u += 0x7fffu + ((u >> 16) & 1u);
    return (ushort)(u >> 16);
}
__device__ __forceinline__ float bf2f(ushort u) {
    return __uint_as_float(((unsigned int)u) << 16);
}

// ---- K0: histogram of dst --------------------------------------------------
__global__ void k_hist(const int* __restrict__ dst, int* __restrict__ cnt, int E) {
    int idx = blockIdx.x * blockDim.x + threadIdx.x;
    int stride = gridDim.x * blockDim.x;
    for (; idx < E; idx += stride) atomicAdd(&cnt[dst[idx]], 1);
}

// ---- K0b: 3-phase parallel scan of (cnt[i]+1) -------------------------------
__global__ __launch_bounds__(1024) void k_scanA(const int* __restrict__ cnt,
                                                int* __restrict__ bsum, int N) {
    __shared__ int ws[16];
    int tt = threadIdx.x, ln = tt & 63, wv = tt >> 6;
    int i = blockIdx.x * 1024 + tt;
    int v = (i < N) ? (cnt[i] + 1) : 0;
#pragma unroll
    for (int s = 32; s > 0; s >>= 1) v += __shfl_xor(v, s);
    if (ln == 0) ws[wv] = v;
    __syncthreads();
    if (tt == 0) {
        int s = 0;
#pragma unroll
        for (int k = 0; k < 16; k++) s += ws[k];
        bsum[blockIdx.x] = s;
    }
}
// nb <= 64 (N <= 65536)
__global__ __launch_bounds__(64) void k_scanB(const int* __restrict__ bsum,
                                              int* __restrict__ bpre,
                                              int* __restrict__ roffN, int nb) {
    int ln = threadIdx.x;
    int v = (ln < nb) ? bsum[ln] : 0;
    int x = v;
#pragma unroll
    for (int off = 1; off < 64; off <<= 1) {
        int y = __shfl_up(x, off);
        if (ln >= off) x += y;
    }
    if (ln < nb) bpre[ln] = x - v;
    if (ln == 63) *roffN = x;
}
__global__ __launch_bounds__(1024) void k_scanC(const int* __restrict__ cnt,
                                                const int* __restrict__ bpre,
                                                int* __restrict__ roff,
                                                int* __restrict__ wpos, int N) {
    __shared__ int ws[16];
    int tt = threadIdx.x, ln = tt & 63, wv = tt >> 6;
    int i = blockIdx.x * 1024 + tt;
    int v = (i < N) ? (cnt[i] + 1) : 0;
    int x = v;
#pragma unroll
    for (int off = 1; off < 64; off <<= 1) {
        int y = __shfl_up(x, off);
        if (ln >= off) x += y;
    }
    if (ln == 63) ws[wv] = x;
    __syncthreads();
    if (wv == 0) {
        int wsv = (ln < 16) ? ws[ln] : 0;
        int xs = wsv;
#pragma unroll
        for (int off = 1; off < 16; off <<= 1) {
            int y = __shfl_up(xs, off);
            if (ln >= off) xs += y;
        }
        if (ln < 16) ws[ln] = xs - wsv;
    }
    __syncthreads();
    int excl = x - v + ws[wv] + bpre[blockIdx.x];
    if (i < N) { roff[i] = excl; wpos[i] = excl; }
}

// ---- K0c: scatter edges into CSR slots ------------------------------------
__global__ void k_scatter(const int* __restrict__ src, const int* __restrict__ dst,
                          int* __restrict__ wpos, int* __restrict__ eidC,
                          int* __restrict__ srcC, int* __restrict__ posC, int E) {
    int idx = blockIdx.x * blockDim.x + threadIdx.x;
    int stride = gridDim.x * blockDim.x;
    for (; idx < E; idx += stride) {
        int d = dst[idx];
        int p = atomicAdd(&wpos[d], 1);
        eidC[p] = idx;
        srcC[p] = src[idx];
        posC[idx] = p;
    }
}

// ---- K1: per-node loop_attr (mean of incident rel) via CSR -----------------
__global__ __launch_bounds__(256) void k_loopcsr(const int* __restrict__ eidC,
                                                 const int* __restrict__ roff,
                                                 const float* __restrict__ rel,
                                                 float* __restrict__ loopat,
                                                 int* __restrict__ srcC, int N) {
    int t = threadIdx.x, ln = t & 63, wv = t >> 6;
    int nw = gridDim.x * 4;
    for (int n = blockIdx.x * 4 + wv; n < N; n += nw) {
        int r0 = roff[n], r1 = roff[n + 1];
        int deg = r1 - r0 - 1;  // real edges (last slot = self)
        float s0 = 0.f, s1 = 0.f, s2 = 0.f, s3 = 0.f;
        int j = 0;
        for (; j + 4 <= deg; j += 4) {
            int e0 = eidC[r0 + j], e1 = eidC[r0 + j + 1];
            int e2 = eidC[r0 + j + 2], e3 = eidC[r0 + j + 3];
            s0 += rel[(long long)e0 * 64 + ln];
            s1 += rel[(long long)e1 * 64 + ln];
            s2 += rel[(long long)e2 * 64 + ln];
            s3 += rel[(long long)e3 * 64 + ln];
        }
        for (; j < deg; j++) s0 += rel[(long long)eidC[r0 + j] * 64 + ln];
        float s = (s0 + s1) + (s2 + s3);
        loopat[(long long)n * 64 + ln] = s / (float)(deg > 0 ? deg : 1);
        if (ln == 0) srcC[r1 - 1] = n;  // self-loop source
    }
}

// ---- K2: y = bf16(x @ W + b), PERMUTED within each 64-col head block -------
// perm(c) = (c&15)*4 + (c>>4). Lane ln computes col cc with perm(cc)==ln.
__global__ __launch_bounds__(512) void k_lin(const float* __restrict__ x,
                                             const float* __restrict__ W,
                                             const float* __restrict__ b,
                                             ushort* __restrict__ y, int N) {
    __shared__ float w[64 * 320];  // 80 KB
    int t = threadIdx.x;
    for (int i = t; i < 64 * 320; i += 512) w[i] = W[i];
    __syncthreads();
    int wv = t >> 6, ln = t & 63;
    int cc = ((ln & 3) << 4) | (ln >> 2);  // col this lane computes
    for (long long base = (long long)blockIdx.x * 8; base < N; base += (long long)gridDim.x * 8) {
        long long node = base + wv;
        bool ok = node < N;
        long long nn = ok ? node : (long long)(N - 1);
        float xv = x[nn * 64 + ln];
        float acc[5];
#pragma unroll
        for (int q = 0; q < 5; q++) acc[q] = b[q * 64 + cc];
        for (int k = 0; k < 64; k++) {
            float xk = __shfl(xv, k);
#pragma unroll
            for (int q = 0; q < 5; q++) acc[q] = fmaf(xk, w[k * 320 + q * 64 + cc], acc[q]);
        }
        if (ok) {
#pragma unroll
            for (int q = 0; q < 5; q++) y[nn * 320 + q * 64 + ln] = f2bf(acc[q]);
        }
    }
}

// ---- K3: fused em-MFMA + logits for ALL rows (edges + self loops) ----------
__global__ __launch_bounds__(512) void k_fused(
    const float* __restrict__ rel, const float* __restrict__ loopat,
    const int* __restrict__ src, const int* __restrict__ dst,
    const ushort* __restrict__ xlbf, const ushort* __restrict__ xrbf,
    const float* __restrict__ Weg, const float* __restrict__ attg,
    const int* __restrict__ posC, const int* __restrict__ roff,
    float* __restrict__ logitsC, int E, int M) {
    __shared__ __align__(16) ushort weT[64 * 320];  // 40 KB
    int t = threadIdx.x;
    for (int idx = t; idx < 64 * 320; idx += 512) {
        int k = idx / 320;
        int n = idx - k * 320;
        int byte = n * 128 + k * 2;
        byte ^= (n & 7) << 4;
        weT[byte >> 1] = f2bf(Weg[idx]);
    }
    __syncthreads();

    int l = t & 63, wv = t >> 6;
    int g = l >> 4, m = l & 15;
    int r0 = (blockIdx.x * 8 + wv) * 32;
    if (r0 >= M) return;

    // A fragments: lane holds ea[row = r0+rt*16+m][k = kh*32 + g*8 + j]
    s8v afr[2][2];
#pragma unroll
    for (int rt = 0; rt < 2; rt++) {
        int row = r0 + rt * 16 + m;
        if (row >= M) row = M - 1;
        const float* ap = (row < E) ? (rel + (long long)row * 64)
                                    : (loopat + (long long)(row - E) * 64);
#pragma unroll
        for (int kh = 0; kh < 2; kh++) {
            const float* p = ap + kh * 32 + g * 8;
            float4 u0 = *(const float4*)(p);
            float4 u1 = *(const float4*)(p + 4);
            s8v a;
            a[0] = (short)f2bf(u0.x); a[1] = (short)f2bf(u0.y);
            a[2] = (short)f2bf(u0.z); a[3] = (short)f2bf(u0.w);
            a[4] = (short)f2bf(u1.x); a[5] = (short)f2bf(u1.y);
            a[6] = (short)f2bf(u1.z); a[7] = (short)f2bf(u1.w);
            afr[rt][kh] = a;
        }
    }

    // hoist src/dst for the 8 epilogue rows of this lane's g-group
    int sarr[2][4], darr[2][4];
#pragma unroll
    for (int rt = 0; rt < 2; rt++)
#pragma unroll
        for (int q = 0; q < 4; q++) {
            int row = r0 + rt * 16 + g * 4 + q;
            int rr = row < M ? row : M - 1;
            int s, d;
            if (rr < E) { s = src[rr]; d = dst[rr]; }
            else        { s = d = rr - E; }
            sarr[rt][q] = s; darr[rt][q] = d;
        }

#pragma unroll
    for (int h = 0; h < 5; h++) {
        f4v acc[4][2];  // [ct][rt]
#pragma unroll
        for (int ct = 0; ct < 4; ct++)
#pragma unroll
            for (int rt = 0; rt < 2; rt++) acc[ct][rt] = (f4v)0.0f;

#pragma unroll
        for (int ct = 0; ct < 4; ct++) {
            int n = h * 64 + ct * 16 + m;
            int b0 = (n * 128 + 0 * 64 + g * 16) ^ ((n & 7) << 4);
            int b1 = (n * 128 + 1 * 64 + g * 16) ^ ((n & 7) << 4);
            s8v bf0 = *(const s8v*)((const char*)weT + b0);
            s8v bf1 = *(const s8v*)((const char*)weT + b1);
#pragma unroll
            for (int rt = 0; rt < 2; rt++) {
                acc[ct][rt] = __builtin_amdgcn_mfma_f32_16x16x32_bf16(afr[rt][0], bf0, acc[ct][rt], 0, 0, 0);
                acc[ct][rt] = __builtin_amdgcn_mfma_f32_16x16x32_bf16(afr[rt][1], bf1, acc[ct][rt], 0, 0, 0);
            }
        }

        float attv[4];
#pragma unroll
        for (int ct = 0; ct < 4; ct++) attv[ct] = attg[h * 64 + ct * 16 + m];

#pragma unroll
        for (int rt = 0; rt < 2; rt++) {
#pragma unroll
            for (int q = 0; q < 4; q++) {
                // permuted layout: element ct of the 8B load <-> col ct*16+m
                s4v xv = *(const s4v*)(xlbf + (long long)sarr[rt][q] * 320 + h * 64 + m * 4);
                s4v rv = *(const s4v*)(xrbf + (long long)darr[rt][q] * 320 + h * 64 + m * 4);
                float sum = 0.f;
#pragma unroll
                for (int ct = 0; ct < 4; ct++) {
                    float v = acc[ct][rt][q] + bf2f((ushort)xv[ct]) + bf2f((ushort)rv[ct]);
                    v = v > 0.f ? v : v * NEGS;
                    sum = fmaf(v, attv[ct], sum);
                }
                sum += __shfl_xor(sum, 1);
                sum += __shfl_xor(sum, 2);
                sum += __shfl_xor(sum, 4);
                sum += __shfl_xor(sum, 8);
                int row = r0 + rt * 16 + g * 4 + q;
                if (row < M && m == 0) {
                    int p = (row < E) ? posC[row] : (roff[row - E + 1] - 1);
                    logitsC[(long long)p * 5 + h] = sum;
                }
            }
        }
    }
}

// ---- K4: per-node softmax + conv accumulation (4 slots in parallel) --------
__global__ __launch_bounds__(256) void k_agg(const float* __restrict__ logitsC,
                                             const int* __restrict__ srcC,
                                             const int* __restrict__ roff,
                                             const ushort* __restrict__ xlbf,
                                             float* __restrict__ conv, int N) {
    int t = threadIdx.x, ln = t & 63, wv = t >> 6;
    int sub = ln >> 4, m = ln & 15;
    int nw = gridDim.x * 4;
    for (int n = blockIdx.x * 4 + wv; n < N; n += nw) {
        int r0 = roff[n], r1 = roff[n + 1];
        int deg = r1 - r0;  // includes self slot
        float mh[5], dh[5];
#pragma unroll
        for (int h = 0; h < 5; h++) {
            float mm = -3.4e38f;
            for (int j = ln; j < deg; j += 64)
                mm = fmaxf(mm, logitsC[(long long)(r0 + j) * 5 + h]);
#pragma unroll
            for (int s = 32; s > 0; s >>= 1) mm = fmaxf(mm, __shfl_xor(mm, s));
            float sden = 0.f;
            for (int j = ln; j < deg; j += 64)
                sden += expf(logitsC[(long long)(r0 + j) * 5 + h] - mm);
            sden = wredsum(sden);
            mh[h] = mm;
            dh[h] = 1.0f / sden;
        }
        // accumulate: 4 slot-groups x 16 lanes; reg j <-> col j*16+m (perm layout)
        float accv[4] = {0.f, 0.f, 0.f, 0.f};
        for (int jj = sub; jj < deg; jj += 4) {
            int slot = r0 + jj;
            int s = srcC[slot];
            const ushort* xp = xlbf + (long long)s * 320 + m * 4;
#pragma unroll
            for (int h = 0; h < 5; h++) {
                float a = expf(logitsC[(long long)slot * 5 + h] - mh[h]) * dh[h];
                s4v xv = *(const s4v*)(xp + h * 64);
#pragma unroll
                for (int j = 0; j < 4; j++) accv[j] = fmaf(a, bf2f((ushort)xv[j]), accv[j]);
            }
        }
#pragma unroll
        for (int j = 0; j < 4; j++) {
            accv[j] += __shfl_xor(accv[j], 16);
            accv[j] += __shfl_xor(accv[j], 32);
        }
        // transpose to natural: lane ln wants col ln = reg (ln>>4) of lane (ln&15)
        float v0 = __shfl(accv[0], m);
        float v1 = __shfl(accv[1], m);
        float v2 = __shfl(accv[2], m);
        float v3 = __shfl(accv[3], m);
        float outv = (sub == 0) ? v0 : (sub == 1) ? v1 : (sub == 2) ? v2 : v3;
        conv[(long long)n * 64 + ln] = outv * 0.2f;
    }
}

// ---- K5: residual + LN -> MFMA MLP(64->128->64) -> residual + LN -----------
__global__ __launch_bounds__(512) void k_mlp(const float* __restrict__ feat,
                                             const float* __restrict__ conv,
                                             const float* __restrict__ cbias,
                                             const float* __restrict__ lng,
                                             const float* __restrict__ lnb,
                                             const float* __restrict__ ln1g,
                                             const float* __restrict__ ln1b,
                                             const float* __restrict__ fcwg,
                                             const float* __restrict__ fcb,
                                             const float* __restrict__ fc1wg,
                                             const float* __restrict__ fc1b,
                                             float* __restrict__ out, int N) {
    __shared__ __align__(16) ushort w1T[64 * 128];   // [n<128][k<64]: byte=n*128+k*2 ^sw
    __shared__ __align__(16) ushort w2T[64 * 128];   // [n<64][k<128]: byte=n*256+k*2 ^sw
    __shared__ __align__(16) ushort tls[8][16 * 128]; // per-wave t: byte=r*256+c*2 ^sw
    __shared__ __align__(16) ushort xnl[8][16 * 64];  // per-wave xn: byte=r*128+c*2 ^sw
    int t = threadIdx.x;
    for (int i = t; i < 8192; i += 512) {
        int k = i >> 7, n = i & 127;
        int by = (n * 128 + k * 2) ^ ((n & 7) << 4);
        w1T[by >> 1] = f2bf(fcwg[i]);
    }
    for (int i = t; i < 8192; i += 512) {
        int k = i >> 6, n = i & 63;
        int by = (n * 256 + k * 2) ^ ((n & 7) << 4);
        w2T[by >> 1] = f2bf(fc1wg[i]);
    }
    __syncthreads();
    int ln = t & 63, wv = t >> 6;
    int g = ln >> 4, m = ln & 15;
    char* tb = (char*)&tls[wv][0];
    char* xb = (char*)&xnl[wv][0];
    // hoisted D-layout params (col = ct*16+m)
    float fcbv[8];
#pragma unroll
    for (int ct = 0; ct < 8; ct++) fcbv[ct] = fcb[ct * 16 + m];
    float fc1bv[4], g1v[4], b1v[4];
#pragma unroll
    for (int ct = 0; ct < 4; ct++) {
        fc1bv[ct] = fc1b[ct * 16 + m];
        g1v[ct] = ln1g[ct * 16 + m];
        b1v[ct] = ln1b[ct * 16 + m];
    }
    int nblk = gridDim.x * 8;
    for (int nb0 = (blockIdx.x * 8 + wv) * 16; nb0 < N; nb0 += nblk * 16) {
        int node = nb0 + m;
        long long nd = (node < N) ? node : (N - 1);
        // load + residual; lane holds node=m, cols kh*32+g*8+j
        float xv[2][8];
#pragma unroll
        for (int kh = 0; kh < 2; kh++) {
            int c0 = kh * 32 + g * 8;
            const float* fp = feat + nd * 64 + c0;
            const float* cp = conv + nd * 64 + c0;
            float4 f0 = *(const float4*)fp, f1 = *(const float4*)(fp + 4);
            float4 q0 = *(const float4*)cp, q1 = *(const float4*)(cp + 4);
            float4 cb0 = *(const float4*)(cbias + c0), cb1 = *(const float4*)(cbias + c0 + 4);
            xv[kh][0] = f0.x + q0.x + cb0.x; xv[kh][1] = f0.y + q0.y + cb0.y;
            xv[kh][2] = f0.z + q0.z + cb0.z; xv[kh][3] = f0.w + q0.w + cb0.w;
            xv[kh][4] = f1.x + q1.x + cb1.x; xv[kh][5] = f1.y + q1.y + cb1.y;
            xv[kh][6] = f1.z + q1.z + cb1.z; xv[kh][7] = f1.w + q1.w + cb1.w;
        }
        // LN1 (reduce over g: lanes m fixed)
        float sm = 0.f;
#pragma unroll
        for (int kh = 0; kh < 2; kh++)
#pragma unroll
            for (int j = 0; j < 8; j++) sm += xv[kh][j];
        sm += __shfl_xor(sm, 16); sm += __shfl_xor(sm, 32);
        float mu = sm * (1.0f / 64.0f);
        float vr = 0.f;
#pragma unroll
        for (int kh = 0; kh < 2; kh++)
#pragma unroll
            for (int j = 0; j < 8; j++) {
                float dv = xv[kh][j] - mu;
                vr += dv * dv;
            }
        vr += __shfl_xor(vr, 16); vr += __shfl_xor(vr, 32);
        float rs = rsqrtf(vr * (1.0f / 64.0f) + LN_EPS);
        s8v af[2];
#pragma unroll
        for (int kh = 0; kh < 2; kh++) {
            int c0 = kh * 32 + g * 8;
            float4 g0 = *(const float4*)(lng + c0), g1 = *(const float4*)(lng + c0 + 4);
            float4 e0 = *(const float4*)(lnb + c0), e1 = *(const float4*)(lnb + c0 + 4);
            float gg[8] = {g0.x, g0.y, g0.z, g0.w, g1.x, g1.y, g1.z, g1.w};
            float bb[8] = {e0.x, e0.y, e0.z, e0.w, e1.x, e1.y, e1.z, e1.w};
#pragma unroll
            for (int j = 0; j < 8; j++)
                af[kh][j] = (short)f2bf((xv[kh][j] - mu) * rs * gg[j] + bb[j]);
            // stash xn (bf16) for the residual, row=m
            int by = (m * 128 + (kh * 32 + g * 8) * 2) ^ ((m & 7) << 4);
            *(s8v*)(xb + by) = af[kh];
        }
        // GEMM1: t = xn @ w1
        f4v a1[8];
#pragma unroll
        for (int ct = 0; ct < 8; ct++) a1[ct] = (f4v)0.0f;
#pragma unroll
        for (int ct = 0; ct < 8; ct++) {
            int n1 = ct * 16 + m;
#pragma unroll
            for (int kh = 0; kh < 2; kh++) {
                int by = (n1 * 128 + (kh * 32 + g * 8) * 2) ^ ((n1 & 7) << 4);
                s8v bf = *(const s8v*)((const char*)w1T + by);
                a1[ct] = __builtin_amdgcn_mfma_f32_16x16x32_bf16(af[kh], bf, a1[ct], 0, 0, 0);
            }
        }
        // t += fcb, cvt bf16, store to tls (row=g*4+q, col=ct*16+m)
#pragma unroll
        for (int ct = 0; ct < 8; ct++)
#pragma unroll
            for (int q = 0; q < 4; q++) {
                int r = g * 4 + q, c = ct * 16 + m;
                int by = (r * 256 + c * 2) ^ ((r & 7) << 4);
                *(ushort*)(tb + by) = f2bf(a1[ct][q] + fcbv[ct]);
            }
        // GEMM2: h = t @ w2
        f4v a2[4];
#pragma unroll
        for (int ct = 0; ct < 4; ct++) a2[ct] = (f4v)0.0f;
#pragma unroll
        for (int kh2 = 0; kh2 < 4; kh2++) {
            int by = (m * 256 + (kh2 * 32 + g * 8) * 2) ^ ((m & 7) << 4);
            s8v a2f = *(const s8v*)(tb + by);
#pragma unroll
            for (int ct = 0; ct < 4; ct++) {
                int n2 = ct * 16 + m;
                int by2 = (n2 * 256 + (kh2 * 32 + g * 8) * 2) ^ ((n2 & 7) << 4);
                s8v bf = *(const s8v*)((const char*)w2T + by2);
                a2[ct] = __builtin_amdgcn_mfma_f32_16x16x32_bf16(a2f, bf, a2[ct], 0, 0, 0);
            }
        }
        // y = xn + h; LN2 per row (reduce over m: masks 1,2,4,8); store natural
#pragma unroll
        for (int q = 0; q < 4; q++) {
            int r = g * 4 + q;
            float yv[4];
#pragma unroll
            for (int ct = 0; ct < 4; ct++) {
                int by = (r * 128 + (ct * 16 + m) * 2) ^ ((r & 7) << 4);
                yv[ct] = bf2f(*(const ushort*)(xb + by)) + a2[ct][q] + fc1bv[ct];
            }
            float sm2 = (yv[0] + yv[1]) + (yv[2] + yv[3]);
            sm2 += __shfl_xor(sm2, 1); sm2 += __shfl_xor(sm2, 2);
            sm2 += __shfl_xor(sm2, 4); sm2 += __shfl_xor(sm2, 8);
            float mu2 = sm2 * (1.0f / 64.0f);
            float vr2 = 0.f;
#pragma unroll
            for (int ct = 0; ct < 4; ct++) {
                float dv = yv[ct] - mu2;
                vr2 += dv * dv;
            }
            vr2 += __shfl_xor(vr2, 1); vr2 += __shfl_xor(vr2, 2);
            vr2 += __shfl_xor(vr2, 4); vr2 += __shfl_xor(vr2, 8);
            float rs2 = rsqrtf(vr2 * (1.0f / 64.0f) + LN_EPS);
            int rn = nb0 + r;
            if (rn < N) {
#pragma unroll
                for (int ct = 0; ct < 4; ct++)
                    out[(long long)rn * 64 + ct * 16 + m] =
                        (yv[ct] - mu2) * rs2 * g1v[ct] + b1v[ct];
            }
        }
    }
}

// ---- launch ----------------------------------------------------------------
extern "C" void kernel_launch(void* const* d_in, const int* in_sizes, int n_in,
                              void* d_out, int out_size, void* d_ws, size_t ws_size,
                              hipStream_t stream) {
    const float* feat = (const float*)d_in[0];
    const int* ei = (const int*)d_in[1];
    const float* rel = (const float*)d_in[2];
    const float* Wl = (const float*)d_in[3];
    const float* bl = (const float*)d_in[4];
    const float* Wr = (const float*)d_in[5];
    const float* br = (const float*)d_in[6];
    const float* We = (const float*)d_in[7];
    const float* att = (const float*)d_in[8];
    const float* cbias = (const float*)d_in[9];
    const float* lng = (const float*)d_in[10];
    const float* lnb = (const float*)d_in[11];
    const float* ln1g = (const float*)d_in[12];
    const float* ln1b = (const float*)d_in[13];
    const float* fcw = (const float*)d_in[14];
    const float* fcb = (const float*)d_in[15];
    const float* fc1w = (const float*)d_in[16];
    const float* fc1b = (const float*)d_in[17];
    float* out = (float*)d_out;

    int N = in_sizes[0] / 64;
    int E = in_sizes[1] / 2;
    int M = E + N;
    const int* src = ei;
    const int* dst = ei + E;
    int nb = (N + 1023) / 1024;

    char* wsb = (char*)d_ws;
    ushort* xlbf = (ushort*)wsb;            wsb += (size_t)N * 320 * 2;
    ushort* xrbf = (ushort*)wsb;            wsb += (size_t)N * 320 * 2;
    float* loopat = (float*)wsb;            wsb += (size_t)N * 64 * 4;
    float* conv = (float*)wsb;              wsb += (size_t)N * 64 * 4;
    float* logitsC = (float*)wsb;           wsb += (size_t)M * 5 * 4;
    int* cnt = (int*)wsb;                   wsb += (size_t)N * 4;
    int* roff = (int*)wsb;                  wsb += (size_t)(N + 1) * 4;
    int* wpos = (int*)wsb;                  wsb += (size_t)N * 4;
    int* eidC = (int*)wsb;                  wsb += (size_t)M * 4;
    int* srcC = (int*)wsb;                  wsb += (size_t)M * 4;
    int* posC = (int*)wsb;                  wsb += (size_t)E * 4;
    int* bsum = (int*)wsb;                  wsb += 64 * 4;
    int* bpre = (int*)wsb;                  wsb += 64 * 4;

    hipMemsetAsync(cnt, 0, (size_t)N * 4, stream);

    k_hist<<<1024, 256, 0, stream>>>(dst, cnt, E);
    k_scanA<<<nb, 1024, 0, stream>>>(cnt, bsum, N);
    k_scanB<<<1, 64, 0, stream>>>(bsum, bpre, &roff[N], nb);
    k_scanC<<<nb, 1024, 0, stream>>>(cnt, bpre, roff, wpos, N);
    k_scatter<<<1024, 256, 0, stream>>>(src, dst, wpos, eidC, srcC, posC, E);
    k_loopcsr<<<2048, 256, 0, stream>>>(eidC, roff, rel, loopat, srcC, N);
    k_lin<<<768, 512, 0, stream>>>(feat, Wl, bl, xlbf, N);
    k_lin<<<768, 512, 0, stream>>>(feat, Wr, br, xrbf, N);
    k_fused<<<(M + 255) / 256, 512, 0, stream>>>(rel, loopat, src, dst, xlbf, xrbf, We, att,
                                                 posC, roff, logitsC, E, M);
    k_agg<<<2048, 256, 0, stream>>>(logitsC, srcC, roff, xlbf, conv, N);
    k_mlp<<<391, 512, 0, stream>>>(feat, conv, cbias, lng, lnb, ln1g, ln1b, fcw, fcb, fc1w, fc1b,
                                   out, N);
}

// Round 5
// 764.928 us; speedup vs baseline: 2.7849x; 1.2074x over previous
//
#include <hip/hip_runtime.h>
#include <hip/hip_bf16.h>
#include <math.h>

#define LN_EPS 1e-5f
#define NEGS 0.2f

typedef short s8v __attribute__((ext_vector_type(8)));
typedef short s4v __attribute__((ext_vector_type(4)));
typedef float f4v __attribute__((ext_vector_type(4)));
typedef unsigned short ushort;

// ---- helpers ---------------------------------------------------------------
__device__ __forceinline__ float wredsum(float v) {
#pragma unroll
    for (int s = 32; s > 0; s >>= 1) v += __shfl_xor(v, s);
    return v;
}
// fp32 -> bf16 round-to-nearest-even
__device__ __forceinline__ ushort f2bf(float x) {
    unsigned int u = __float_as_uint(x);
    u += 0x7fffu + ((u >> 16) & 1u);
    return (ushort)(u >> 16);
}
__device__ __forceinline__ float bf2f(ushort u) {
    return __uint_as_float(((unsigned int)u) << 16);
}

// ---- K0: histogram of dst --------------------------------------------------
__global__ void k_hist(const int* __restrict__ dst, int* __restrict__ cnt, int E) {
    int idx = blockIdx.x * blockDim.x + threadIdx.x;
    int stride = gridDim.x * blockDim.x;
    for (; idx < E; idx += stride) atomicAdd(&cnt[dst[idx]], 1);
}

// ---- K0b: 3-phase parallel scan of (cnt[i]+1) -------------------------------
__global__ __launch_bounds__(1024) void k_scanA(const int* __restrict__ cnt,
                                                int* __restrict__ bsum, int N) {
    __shared__ int ws[16];
    int tt = threadIdx.x, ln = tt & 63, wv = tt >> 6;
    int i = blockIdx.x * 1024 + tt;
    int v = (i < N) ? (cnt[i] + 1) : 0;
#pragma unroll
    for (int s = 32; s > 0; s >>= 1) v += __shfl_xor(v, s);
    if (ln == 0) ws[wv] = v;
    __syncthreads();
    if (tt == 0) {
        int s = 0;
#pragma unroll
        for (int k = 0; k < 16; k++) s += ws[k];
        bsum[blockIdx.x] = s;
    }
}
// nb <= 64 (N <= 65536)
__global__ __launch_bounds__(64) void k_scanB(const int* __restrict__ bsum,
                                              int* __restrict__ bpre,
                                              int* __restrict__ roffN, int nb) {
    int ln = threadIdx.x;
    int v = (ln < nb) ? bsum[ln] : 0;
    int x = v;
#pragma unroll
    for (int off = 1; off < 64; off <<= 1) {
        int y = __shfl_up(x, off);
        if (ln >= off) x += y;
    }
    if (ln < nb) bpre[ln] = x - v;
    if (ln == 63) *roffN = x;
}
__global__ __launch_bounds__(1024) void k_scanC(const int* __restrict__ cnt,
                                                const int* __restrict__ bpre,
                                                int* __restrict__ roff,
                                                int* __restrict__ wpos, int N) {
    __shared__ int ws[16];
    int tt = threadIdx.x, ln = tt & 63, wv = tt >> 6;
    int i = blockIdx.x * 1024 + tt;
    int v = (i < N) ? (cnt[i] + 1) : 0;
    int x = v;
#pragma unroll
    for (int off = 1; off < 64; off <<= 1) {
        int y = __shfl_up(x, off);
        if (ln >= off) x += y;
    }
    if (ln == 63) ws[wv] = x;
    __syncthreads();
    if (wv == 0) {
        int wsv = (ln < 16) ? ws[ln] : 0;
        int xs = wsv;
#pragma unroll
        for (int off = 1; off < 16; off <<= 1) {
            int y = __shfl_up(xs, off);
            if (ln >= off) xs += y;
        }
        if (ln < 16) ws[ln] = xs - wsv;
    }
    __syncthreads();
    int excl = x - v + ws[wv] + bpre[blockIdx.x];
    if (i < N) { roff[i] = excl; wpos[i] = excl; }
}

// ---- K0c: scatter edges into CSR slots ------------------------------------
__global__ void k_scatter(const int* __restrict__ src, const int* __restrict__ dst,
                          int* __restrict__ wpos, int* __restrict__ eidC,
                          int* __restrict__ srcC, int* __restrict__ posC, int E) {
    int idx = blockIdx.x * blockDim.x + threadIdx.x;
    int stride = gridDim.x * blockDim.x;
    for (; idx < E; idx += stride) {
        int d = dst[idx];
        int p = atomicAdd(&wpos[d], 1);
        eidC[p] = idx;
        srcC[p] = src[idx];
        posC[idx] = p;
    }
}

// ---- K1: per-node loop_attr (mean of incident rel) via CSR -----------------
__global__ __launch_bounds__(256) void k_loopcsr(const int* __restrict__ eidC,
                                                 const int* __restrict__ roff,
                                                 const float* __restrict__ rel,
                                                 float* __restrict__ loopat,
                                                 int* __restrict__ srcC, int N) {
    int t = threadIdx.x, ln = t & 63, wv = t >> 6;
    int nw = gridDim.x * 4;
    for (int n = blockIdx.x * 4 + wv; n < N; n += nw) {
        int r0 = roff[n], r1 = roff[n + 1];
        int deg = r1 - r0 - 1;  // real edges (last slot = self)
        float s0 = 0.f, s1 = 0.f, s2 = 0.f, s3 = 0.f;
        int j = 0;
        for (; j + 4 <= deg; j += 4) {
            int e0 = eidC[r0 + j], e1 = eidC[r0 + j + 1];
            int e2 = eidC[r0 + j + 2], e3 = eidC[r0 + j + 3];
            s0 += rel[(long long)e0 * 64 + ln];
            s1 += rel[(long long)e1 * 64 + ln];
            s2 += rel[(long long)e2 * 64 + ln];
            s3 += rel[(long long)e3 * 64 + ln];
        }
        for (; j < deg; j++) s0 += rel[(long long)eidC[r0 + j] * 64 + ln];
        float s = (s0 + s1) + (s2 + s3);
        loopat[(long long)n * 64 + ln] = s / (float)(deg > 0 ? deg : 1);
        if (ln == 0) srcC[r1 - 1] = n;  // self-loop source
    }
}

// ---- K2: y = bf16(x @ W + b), PERMUTED within each 64-col head block -------
// perm(c) = (c&15)*4 + (c>>4). Lane ln computes col cc with perm(cc)==ln.
__global__ __launch_bounds__(512) void k_lin(const float* __restrict__ x,
                                             const float* __restrict__ W,
                                             const float* __restrict__ b,
                                             ushort* __restrict__ y, int N) {
    __shared__ float w[64 * 320];  // 80 KB
    int t = threadIdx.x;
    for (int i = t; i < 64 * 320; i += 512) w[i] = W[i];
    __syncthreads();
    int wv = t >> 6, ln = t & 63;
    int cc = ((ln & 3) << 4) | (ln >> 2);  // col this lane computes
    for (long long base = (long long)blockIdx.x * 8; base < N; base += (long long)gridDim.x * 8) {
        long long node = base + wv;
        bool ok = node < N;
        long long nn = ok ? node : (long long)(N - 1);
        float xv = x[nn * 64 + ln];
        float acc[5];
#pragma unroll
        for (int q = 0; q < 5; q++) acc[q] = b[q * 64 + cc];
        for (int k = 0; k < 64; k++) {
            float xk = __shfl(xv, k);
#pragma unroll
            for (int q = 0; q < 5; q++) acc[q] = fmaf(xk, w[k * 320 + q * 64 + cc], acc[q]);
        }
        if (ok) {
#pragma unroll
            for (int q = 0; q < 5; q++) y[nn * 320 + q * 64 + ln] = f2bf(acc[q]);
        }
    }
}

// ---- K3: fused em-MFMA + logits, 16 rows/wave, head-pipelined --------------
__global__ __launch_bounds__(512) void k_fused(
    const float* __restrict__ rel, const float* __restrict__ loopat,
    const int* __restrict__ src, const int* __restrict__ dst,
    const ushort* __restrict__ xlbf, const ushort* __restrict__ xrbf,
    const float* __restrict__ Weg, const float* __restrict__ attg,
    const int* __restrict__ posC, const int* __restrict__ roff,
    float* __restrict__ logitsC, int E, int M) {
    __shared__ __align__(16) ushort weT[64 * 320];  // 40 KB
    int t = threadIdx.x;
    for (int idx = t; idx < 64 * 320; idx += 512) {
        int k = idx / 320;
        int n = idx - k * 320;
        int byte = n * 128 + k * 2;
        byte ^= (n & 7) << 4;
        weT[byte >> 1] = f2bf(Weg[idx]);
    }
    __syncthreads();

    int l = t & 63, wv = t >> 6;
    int g = l >> 4, m = l & 15;
    int r0 = (blockIdx.x * 8 + wv) * 16;
    if (r0 >= M) return;

    // A fragment: lane holds ea[row = r0+m][k = kh*32 + g*8 + j]
    s8v afr[2];
    {
        int row = r0 + m;
        if (row >= M) row = M - 1;
        const float* ap = (row < E) ? (rel + (long long)row * 64)
                                    : (loopat + (long long)(row - E) * 64);
#pragma unroll
        for (int kh = 0; kh < 2; kh++) {
            const float* p = ap + kh * 32 + g * 8;
            float4 u0 = *(const float4*)(p);
            float4 u1 = *(const float4*)(p + 4);
            s8v a;
            a[0] = (short)f2bf(u0.x); a[1] = (short)f2bf(u0.y);
            a[2] = (short)f2bf(u0.z); a[3] = (short)f2bf(u0.w);
            a[4] = (short)f2bf(u1.x); a[5] = (short)f2bf(u1.y);
            a[6] = (short)f2bf(u1.z); a[7] = (short)f2bf(u1.w);
            afr[kh] = a;
        }
    }

    // epilogue rows for this lane: r0 + g*4 + q
    const ushort* xptr[4];
    const ushort* rptr[4];
    int parr[4];
    bool vld[4];
#pragma unroll
    for (int q = 0; q < 4; q++) {
        int row = r0 + g * 4 + q;
        vld[q] = row < M;
        int rr = vld[q] ? row : (M - 1);
        int s, d, p;
        if (rr < E) { s = src[rr]; d = dst[rr]; p = posC[rr]; }
        else        { s = d = rr - E; p = roff[rr - E + 1] - 1; }
        xptr[q] = xlbf + (long long)s * 320 + m * 4;
        rptr[q] = xrbf + (long long)d * 320 + m * 4;
        parr[q] = p;
    }

    // double-buffered per-head gathers (static indices via full unroll)
    s4v xb[2][4], rb[2][4];
    float attb[2][4];
#pragma unroll
    for (int q = 0; q < 4; q++) {
        xb[0][q] = *(const s4v*)(xptr[q]);
        rb[0][q] = *(const s4v*)(rptr[q]);
    }
#pragma unroll
    for (int ct = 0; ct < 4; ct++) attb[0][ct] = attg[ct * 16 + m];

#pragma unroll
    for (int h = 0; h < 5; h++) {
        // prefetch head h+1 while head h computes
        if (h < 4) {
#pragma unroll
            for (int q = 0; q < 4; q++) {
                xb[(h + 1) & 1][q] = *(const s4v*)(xptr[q] + (h + 1) * 64);
                rb[(h + 1) & 1][q] = *(const s4v*)(rptr[q] + (h + 1) * 64);
            }
#pragma unroll
            for (int ct = 0; ct < 4; ct++)
                attb[(h + 1) & 1][ct] = attg[(h + 1) * 64 + ct * 16 + m];
        }

        f4v acc[4];
#pragma unroll
        for (int ct = 0; ct < 4; ct++) acc[ct] = (f4v)0.0f;
#pragma unroll
        for (int ct = 0; ct < 4; ct++) {
            int n = h * 64 + ct * 16 + m;
            int b0 = (n * 128 + 0 * 64 + g * 16) ^ ((n & 7) << 4);
            int b1 = (n * 128 + 1 * 64 + g * 16) ^ ((n & 7) << 4);
            s8v bf0 = *(const s8v*)((const char*)weT + b0);
            s8v bf1 = *(const s8v*)((const char*)weT + b1);
            acc[ct] = __builtin_amdgcn_mfma_f32_16x16x32_bf16(afr[0], bf0, acc[ct], 0, 0, 0);
            acc[ct] = __builtin_amdgcn_mfma_f32_16x16x32_bf16(afr[1], bf1, acc[ct], 0, 0, 0);
        }

#pragma unroll
        for (int q = 0; q < 4; q++) {
            float sum = 0.f;
#pragma unroll
            for (int ct = 0; ct < 4; ct++) {
                float v = acc[ct][q] + bf2f((ushort)xb[h & 1][q][ct])
                                     + bf2f((ushort)rb[h & 1][q][ct]);
                v = v > 0.f ? v : v * NEGS;
                sum = fmaf(v, attb[h & 1][ct], sum);
            }
            sum += __shfl_xor(sum, 1);
            sum += __shfl_xor(sum, 2);
            sum += __shfl_xor(sum, 4);
            sum += __shfl_xor(sum, 8);
            if (vld[q] && m == 0) logitsC[(long long)parr[q] * 5 + h] = sum;
        }
    }
}

// ---- K4: per-node softmax (no max-shift; logits are small) + conv ----------
__global__ __launch_bounds__(256) void k_agg(const float* __restrict__ logitsC,
                                             const int* __restrict__ srcC,
                                             const int* __restrict__ roff,
                                             const ushort* __restrict__ xlbf,
                                             float* __restrict__ conv, int N) {
    int t = threadIdx.x, ln = t & 63, wv = t >> 6;
    int sub = ln >> 4, m = ln & 15;
    int nw = gridDim.x * 4;
    for (int n = blockIdx.x * 4 + wv; n < N; n += nw) {
        int r0 = roff[n], r1 = roff[n + 1];
        int deg = r1 - r0;  // includes self slot
        // pass 1: denominators (no max subtraction; |logit| < ~8 guaranteed)
        float se[5] = {0.f, 0.f, 0.f, 0.f, 0.f};
        for (int j = ln; j < deg; j += 64) {
            long long base = (long long)(r0 + j) * 5;
#pragma unroll
            for (int h = 0; h < 5; h++) se[h] += expf(logitsC[base + h]);
        }
        float dh[5];
#pragma unroll
        for (int h = 0; h < 5; h++) dh[h] = 1.0f / wredsum(se[h]);
        // pass 2: accumulate; 4 slot-groups x 16 lanes; reg j <-> col j*16+m
        float accv[4] = {0.f, 0.f, 0.f, 0.f};
        for (int jj = sub; jj < deg; jj += 4) {
            int slot = r0 + jj;
            int s = srcC[slot];
            const ushort* xp = xlbf + (long long)s * 320 + m * 4;
            long long lb = (long long)slot * 5;
#pragma unroll
            for (int h = 0; h < 5; h++) {
                float a = expf(logitsC[lb + h]) * dh[h];
                s4v xv = *(const s4v*)(xp + h * 64);
#pragma unroll
                for (int j = 0; j < 4; j++) accv[j] = fmaf(a, bf2f((ushort)xv[j]), accv[j]);
            }
        }
#pragma unroll
        for (int j = 0; j < 4; j++) {
            accv[j] += __shfl_xor(accv[j], 16);
            accv[j] += __shfl_xor(accv[j], 32);
        }
        // transpose to natural: lane ln wants col ln = reg (ln>>4) of lane (ln&15)
        float v0 = __shfl(accv[0], m);
        float v1 = __shfl(accv[1], m);
        float v2 = __shfl(accv[2], m);
        float v3 = __shfl(accv[3], m);
        float outv = (sub == 0) ? v0 : (sub == 1) ? v1 : (sub == 2) ? v2 : v3;
        conv[(long long)n * 64 + ln] = outv * 0.2f;
    }
}

// ---- K5: residual + LN -> MFMA MLP(64->128->64) -> residual + LN -----------
__global__ __launch_bounds__(512) void k_mlp(const float* __restrict__ feat,
                                             const float* __restrict__ conv,
                                             const float* __restrict__ cbias,
                                             const float* __restrict__ lng,
                                             const float* __restrict__ lnb,
                                             const float* __restrict__ ln1g,
                                             const float* __restrict__ ln1b,
                                             const float* __restrict__ fcwg,
                                             const float* __restrict__ fcb,
                                             const float* __restrict__ fc1wg,
                                             const float* __restrict__ fc1b,
                                             float* __restrict__ out, int N) {
    __shared__ __align__(16) ushort w1T[64 * 128];   // [n<128][k<64]: byte=n*128+k*2 ^sw
    __shared__ __align__(16) ushort w2T[64 * 128];   // [n<64][k<128]: byte=n*256+k*2 ^sw
    __shared__ __align__(16) ushort tls[8][16 * 128]; // per-wave t: byte=r*256+c*2 ^sw
    __shared__ __align__(16) ushort xnl[8][16 * 64];  // per-wave xn: byte=r*128+c*2 ^sw
    int t = threadIdx.x;
    for (int i = t; i < 8192; i += 512) {
        int k = i >> 7, n = i & 127;
        int by = (n * 128 + k * 2) ^ ((n & 7) << 4);
        w1T[by >> 1] = f2bf(fcwg[i]);
    }
    for (int i = t; i < 8192; i += 512) {
        int k = i >> 6, n = i & 63;
        int by = (n * 256 + k * 2) ^ ((n & 7) << 4);
        w2T[by >> 1] = f2bf(fc1wg[i]);
    }
    __syncthreads();
    int ln = t & 63, wv = t >> 6;
    int g = ln >> 4, m = ln & 15;
    char* tb = (char*)&tls[wv][0];
    char* xb = (char*)&xnl[wv][0];
    float fcbv[8];
#pragma unroll
    for (int ct = 0; ct < 8; ct++) fcbv[ct] = fcb[ct * 16 + m];
    float fc1bv[4], g1v[4], b1v[4];
#pragma unroll
    for (int ct = 0; ct < 4; ct++) {
        fc1bv[ct] = fc1b[ct * 16 + m];
        g1v[ct] = ln1g[ct * 16 + m];
        b1v[ct] = ln1b[ct * 16 + m];
    }
    int nblk = gridDim.x * 8;
    for (int nb0 = (blockIdx.x * 8 + wv) * 16; nb0 < N; nb0 += nblk * 16) {
        int node = nb0 + m;
        long long nd = (node < N) ? node : (N - 1);
        float xv[2][8];
#pragma unroll
        for (int kh = 0; kh < 2; kh++) {
            int c0 = kh * 32 + g * 8;
            const float* fp = feat + nd * 64 + c0;
            const float* cp = conv + nd * 64 + c0;
            float4 f0 = *(const float4*)fp, f1 = *(const float4*)(fp + 4);
            float4 q0 = *(const float4*)cp, q1 = *(const float4*)(cp + 4);
            float4 cb0 = *(const float4*)(cbias + c0), cb1 = *(const float4*)(cbias + c0 + 4);
            xv[kh][0] = f0.x + q0.x + cb0.x; xv[kh][1] = f0.y + q0.y + cb0.y;
            xv[kh][2] = f0.z + q0.z + cb0.z; xv[kh][3] = f0.w + q0.w + cb0.w;
            xv[kh][4] = f1.x + q1.x + cb1.x; xv[kh][5] = f1.y + q1.y + cb1.y;
            xv[kh][6] = f1.z + q1.z + cb1.z; xv[kh][7] = f1.w + q1.w + cb1.w;
        }
        float sm = 0.f;
#pragma unroll
        for (int kh = 0; kh < 2; kh++)
#pragma unroll
            for (int j = 0; j < 8; j++) sm += xv[kh][j];
        sm += __shfl_xor(sm, 16); sm += __shfl_xor(sm, 32);
        float mu = sm * (1.0f / 64.0f);
        float vr = 0.f;
#pragma unroll
        for (int kh = 0; kh < 2; kh++)
#pragma unroll
            for (int j = 0; j < 8; j++) {
                float dv = xv[kh][j] - mu;
                vr += dv * dv;
            }
        vr += __shfl_xor(vr, 16); vr += __shfl_xor(vr, 32);
        float rs = rsqrtf(vr * (1.0f / 64.0f) + LN_EPS);
        s8v af[2];
#pragma unroll
        for (int kh = 0; kh < 2; kh++) {
            int c0 = kh * 32 + g * 8;
            float4 g0 = *(const float4*)(lng + c0), g1 = *(const float4*)(lng + c0 + 4);
            float4 e0 = *(const float4*)(lnb + c0), e1 = *(const float4*)(lnb + c0 + 4);
            float gg[8] = {g0.x, g0.y, g0.z, g0.w, g1.x, g1.y, g1.z, g1.w};
            float bb[8] = {e0.x, e0.y, e0.z, e0.w, e1.x, e1.y, e1.z, e1.w};
#pragma unroll
            for (int j = 0; j < 8; j++)
                af[kh][j] = (short)f2bf((xv[kh][j] - mu) * rs * gg[j] + bb[j]);
            int by = (m * 128 + (kh * 32 + g * 8) * 2) ^ ((m & 7) << 4);
            *(s8v*)(xb + by) = af[kh];
        }
        f4v a1[8];
#pragma unroll
        for (int ct = 0; ct < 8; ct++) a1[ct] = (f4v)0.0f;
#pragma unroll
        for (int ct = 0; ct < 8; ct++) {
            int n1 = ct * 16 + m;
#pragma unroll
            for (int kh = 0; kh < 2; kh++) {
                int by = (n1 * 128 + (kh * 32 + g * 8) * 2) ^ ((n1 & 7) << 4);
                s8v bf = *(const s8v*)((const char*)w1T + by);
                a1[ct] = __builtin_amdgcn_mfma_f32_16x16x32_bf16(af[kh], bf, a1[ct], 0, 0, 0);
            }
        }
#pragma unroll
        for (int ct = 0; ct < 8; ct++)
#pragma unroll
            for (int q = 0; q < 4; q++) {
                int r = g * 4 + q, c = ct * 16 + m;
                int by = (r * 256 + c * 2) ^ ((r & 7) << 4);
                *(ushort*)(tb + by) = f2bf(a1[ct][q] + fcbv[ct]);
            }
        f4v a2[4];
#pragma unroll
        for (int ct = 0; ct < 4; ct++) a2[ct] = (f4v)0.0f;
#pragma unroll
        for (int kh2 = 0; kh2 < 4; kh2++) {
            int by = (m * 256 + (kh2 * 32 + g * 8) * 2) ^ ((m & 7) << 4);
            s8v a2f = *(const s8v*)(tb + by);
#pragma unroll
            for (int ct = 0; ct < 4; ct++) {
                int n2 = ct * 16 + m;
                int by2 = (n2 * 256 + (kh2 * 32 + g * 8) * 2) ^ ((n2 & 7) << 4);
                s8v bf = *(const s8v*)((const char*)w2T + by2);
                a2[ct] = __builtin_amdgcn_mfma_f32_16x16x32_bf16(a2f, bf, a2[ct], 0, 0, 0);
            }
        }
#pragma unroll
        for (int q = 0; q < 4; q++) {
            int r = g * 4 + q;
            float yv[4];
#pragma unroll
            for (int ct = 0; ct < 4; ct++) {
                int by = (r * 128 + (ct * 16 + m) * 2) ^ ((r & 7) << 4);
                yv[ct] = bf2f(*(const ushort*)(xb + by)) + a2[ct][q] + fc1bv[ct];
            }
            float sm2 = (yv[0] + yv[1]) + (yv[2] + yv[3]);
            sm2 += __shfl_xor(sm2, 1); sm2 += __shfl_xor(sm2, 2);
            sm2 += __shfl_xor(sm2, 4); sm2 += __shfl_xor(sm2, 8);
            float mu2 = sm2 * (1.0f / 64.0f);
            float vr2 = 0.f;
#pragma unroll
            for (int ct = 0; ct < 4; ct++) {
                float dv = yv[ct] - mu2;
                vr2 += dv * dv;
            }
            vr2 += __shfl_xor(vr2, 1); vr2 += __shfl_xor(vr2, 2);
            vr2 += __shfl_xor(vr2, 4); vr2 += __shfl_xor(vr2, 8);
            float rs2 = rsqrtf(vr2 * (1.0f / 64.0f) + LN_EPS);
            int rn = nb0 + r;
            if (rn < N) {
#pragma unroll
                for (int ct = 0; ct < 4; ct++)
                    out[(long long)rn * 64 + ct * 16 + m] =
                        (yv[ct] - mu2) * rs2 * g1v[ct] + b1v[ct];
            }
        }
    }
}

// ---- launch ----------------------------------------------------------------
extern "C" void kernel_launch(void* const* d_in, const int* in_sizes, int n_in,
                              void* d_out, int out_size, void* d_ws, size_t ws_size,
                              hipStream_t stream) {
    const float* feat = (const float*)d_in[0];
    const int* ei = (const int*)d_in[1];
    const float* rel = (const float*)d_in[2];
    const float* Wl = (const float*)d_in[3];
    const float* bl = (const float*)d_in[4];
    const float* Wr = (const float*)d_in[5];
    const float* br = (const float*)d_in[6];
    const float* We = (const float*)d_in[7];
    const float* att = (const float*)d_in[8];
    const float* cbias = (const float*)d_in[9];
    const float* lng = (const float*)d_in[10];
    const float* lnb = (const float*)d_in[11];
    const float* ln1g = (const float*)d_in[12];
    const float* ln1b = (const float*)d_in[13];
    const float* fcw = (const float*)d_in[14];
    const float* fcb = (const float*)d_in[15];
    const float* fc1w = (const float*)d_in[16];
    const float* fc1b = (const float*)d_in[17];
    float* out = (float*)d_out;

    int N = in_sizes[0] / 64;
    int E = in_sizes[1] / 2;
    int M = E + N;
    const int* src = ei;
    const int* dst = ei + E;
    int nb = (N + 1023) / 1024;

    char* wsb = (char*)d_ws;
    ushort* xlbf = (ushort*)wsb;            wsb += (size_t)N * 320 * 2;
    ushort* xrbf = (ushort*)wsb;            wsb += (size_t)N * 320 * 2;
    float* loopat = (float*)wsb;            wsb += (size_t)N * 64 * 4;
    float* conv = (float*)wsb;              wsb += (size_t)N * 64 * 4;
    float* logitsC = (float*)wsb;           wsb += (size_t)M * 5 * 4;
    int* cnt = (int*)wsb;                   wsb += (size_t)N * 4;
    int* roff = (int*)wsb;                  wsb += (size_t)(N + 1) * 4;
    int* wpos = (int*)wsb;                  wsb += (size_t)N * 4;
    int* eidC = (int*)wsb;                  wsb += (size_t)M * 4;
    int* srcC = (int*)wsb;                  wsb += (size_t)M * 4;
    int* posC = (int*)wsb;                  wsb += (size_t)E * 4;
    int* bsum = (int*)wsb;                  wsb += 64 * 4;
    int* bpre = (int*)wsb;                  wsb += 64 * 4;

    hipMemsetAsync(cnt, 0, (size_t)N * 4, stream);

    k_hist<<<1024, 256, 0, stream>>>(dst, cnt, E);
    k_scanA<<<nb, 1024, 0, stream>>>(cnt, bsum, N);
    k_scanB<<<1, 64, 0, stream>>>(bsum, bpre, &roff[N], nb);
    k_scanC<<<nb, 1024, 0, stream>>>(cnt, bpre, roff, wpos, N);
    k_scatter<<<1024, 256, 0, stream>>>(src, dst, wpos, eidC, srcC, posC, E);
    k_loopcsr<<<2048, 256, 0, stream>>>(eidC, roff, rel, loopat, srcC, N);
    k_lin<<<768, 512, 0, stream>>>(feat, Wl, bl, xlbf, N);
    k_lin<<<768, 512, 0, stream>>>(feat, Wr, br, xrbf, N);
    k_fused<<<(M + 127) / 128, 512, 0, stream>>>(rel, loopat, src, dst, xlbf, xrbf, We, att,
                                                 posC, roff, logitsC, E, M);
    k_agg<<<2048, 256, 0, stream>>>(logitsC, srcC, roff, xlbf, conv, N);
    k_mlp<<<391, 512, 0, stream>>>(feat, conv, cbias, lng, lnb, ln1g, ln1b, fcw, fcb, fc1w, fc1b,
                                   out, N);
}

// Round 7
// 644.777 us; speedup vs baseline: 3.3039x; 1.1863x over previous
//
#include <hip/hip_runtime.h>
#include <hip/hip_bf16.h>
#include <math.h>

#define LN_EPS 1e-5f
#define NEGS 0.2f

typedef short s8v __attribute__((ext_vector_type(8)));
typedef short s4v __attribute__((ext_vector_type(4)));
typedef float f4v __attribute__((ext_vector_type(4)));
typedef unsigned short ushort;

// ---- helpers ---------------------------------------------------------------
__device__ __forceinline__ float wredsum(float v) {
#pragma unroll
    for (int s = 32; s > 0; s >>= 1) v += __shfl_xor(v, s);
    return v;
}
// fp32 -> bf16 (compiler cvt; pairs pack to v_cvt_pk_bf16_f32)
__device__ __forceinline__ ushort f2bf(float x) {
    union { __hip_bfloat16 h; ushort u; } c;
    c.h = __float2bfloat16(x);
    return c.u;
}
__device__ __forceinline__ float bf2f(ushort u) {
    return __uint_as_float(((unsigned int)u) << 16);
}

// ---- K0: histogram of dst --------------------------------------------------
__global__ void k_hist(const int* __restrict__ dst, int* __restrict__ cnt, int E) {
    int idx = blockIdx.x * blockDim.x + threadIdx.x;
    int stride = gridDim.x * blockDim.x;
    for (; idx < E; idx += stride) atomicAdd(&cnt[dst[idx]], 1);
}

// ---- K0b: 3-phase parallel scan of (cnt[i]+1) -------------------------------
__global__ __launch_bounds__(1024) void k_scanA(const int* __restrict__ cnt,
                                                int* __restrict__ bsum, int N) {
    __shared__ int ws[16];
    int tt = threadIdx.x, ln = tt & 63, wv = tt >> 6;
    int i = blockIdx.x * 1024 + tt;
    int v = (i < N) ? (cnt[i] + 1) : 0;
#pragma unroll
    for (int s = 32; s > 0; s >>= 1) v += __shfl_xor(v, s);
    if (ln == 0) ws[wv] = v;
    __syncthreads();
    if (tt == 0) {
        int s = 0;
#pragma unroll
        for (int k = 0; k < 16; k++) s += ws[k];
        bsum[blockIdx.x] = s;
    }
}
// nb <= 64 (N <= 65536)
__global__ __launch_bounds__(64) void k_scanB(const int* __restrict__ bsum,
                                              int* __restrict__ bpre,
                                              int* __restrict__ roffN, int nb) {
    int ln = threadIdx.x;
    int v = (ln < nb) ? bsum[ln] : 0;
    int x = v;
#pragma unroll
    for (int off = 1; off < 64; off <<= 1) {
        int y = __shfl_up(x, off);
        if (ln >= off) x += y;
    }
    if (ln < nb) bpre[ln] = x - v;
    if (ln == 63) *roffN = x;
}
__global__ __launch_bounds__(1024) void k_scanC(const int* __restrict__ cnt,
                                                const int* __restrict__ bpre,
                                                int* __restrict__ roff,
                                                int* __restrict__ wpos, int N) {
    __shared__ int ws[16];
    int tt = threadIdx.x, ln = tt & 63, wv = tt >> 6;
    int i = blockIdx.x * 1024 + tt;
    int v = (i < N) ? (cnt[i] + 1) : 0;
    int x = v;
#pragma unroll
    for (int off = 1; off < 64; off <<= 1) {
        int y = __shfl_up(x, off);
        if (ln >= off) x += y;
    }
    if (ln == 63) ws[wv] = x;
    __syncthreads();
    if (wv == 0) {
        int wsv = (ln < 16) ? ws[ln] : 0;
        int xs = wsv;
#pragma unroll
        for (int off = 1; off < 16; off <<= 1) {
            int y = __shfl_up(xs, off);
            if (ln >= off) xs += y;
        }
        if (ln < 16) ws[ln] = xs - wsv;
    }
    __syncthreads();
    int excl = x - v + ws[wv] + bpre[blockIdx.x];
    if (i < N) { roff[i] = excl; wpos[i] = excl; }
}

// ---- K0c: scatter edges into CSR slots ------------------------------------
__global__ void k_scatter(const int* __restrict__ src, const int* __restrict__ dst,
                          int* __restrict__ wpos, int* __restrict__ eidC,
                          int* __restrict__ srcC, int* __restrict__ posC, int E) {
    int idx = blockIdx.x * blockDim.x + threadIdx.x;
    int stride = gridDim.x * blockDim.x;
    for (; idx < E; idx += stride) {
        int d = dst[idx];
        int p = atomicAdd(&wpos[d], 1);
        eidC[p] = idx;
        srcC[p] = src[idx];
        posC[idx] = p;
    }
}

// ---- K1: per-node loop_attr (mean of incident rel) via CSR -----------------
__global__ __launch_bounds__(256) void k_loopcsr(const int* __restrict__ eidC,
                                                 const int* __restrict__ roff,
                                                 const float* __restrict__ rel,
                                                 float* __restrict__ loopat,
                                                 int* __restrict__ srcC, int N) {
    int t = threadIdx.x, ln = t & 63, wv = t >> 6;
    int nw = gridDim.x * 4;
    for (int n = blockIdx.x * 4 + wv; n < N; n += nw) {
        int r0 = roff[n], r1 = roff[n + 1];
        int deg = r1 - r0 - 1;  // real edges (last slot = self)
        float s0 = 0.f, s1 = 0.f, s2 = 0.f, s3 = 0.f;
        int j = 0;
        for (; j + 4 <= deg; j += 4) {
            int e0 = eidC[r0 + j], e1 = eidC[r0 + j + 1];
            int e2 = eidC[r0 + j + 2], e3 = eidC[r0 + j + 3];
            s0 += rel[(long long)e0 * 64 + ln];
            s1 += rel[(long long)e1 * 64 + ln];
            s2 += rel[(long long)e2 * 64 + ln];
            s3 += rel[(long long)e3 * 64 + ln];
        }
        for (; j < deg; j++) s0 += rel[(long long)eidC[r0 + j] * 64 + ln];
        float s = (s0 + s1) + (s2 + s3);
        loopat[(long long)n * 64 + ln] = s / (float)(deg > 0 ? deg : 1);
        if (ln == 0) srcC[r1 - 1] = n;  // self-loop source
    }
}

// ---- K2: MFMA linear: xl = bf16(feat@Wl+bl), xr = bf16(feat@Wr+br) ---------
// Output layout: permuted within each 64-col head block, pos m*4+ct <-> col ct*16+m.
__global__ __launch_bounds__(512) void k_linC(const float* __restrict__ feat,
                                              const float* __restrict__ Wlg,
                                              const float* __restrict__ blg,
                                              const float* __restrict__ Wrg,
                                              const float* __restrict__ brg,
                                              ushort* __restrict__ xlbf,
                                              ushort* __restrict__ xrbf, int N) {
    __shared__ __align__(16) ushort wT[2][64 * 320];  // 80 KB, byte=n*128+k*2 ^ ((n&7)<<4)
    int t = threadIdx.x;
    for (int i = t; i < 5120; i += 512) {  // 2 mats x 320 n x 8 kb
        int mat = i >= 2560;
        int j = mat ? (i - 2560) : i;      // FIX: was i & 2559 (not a pow2-1 mask!)
        int n = j >> 3, kb = j & 7;
        const float* W = mat ? Wrg : Wlg;
        s8v v;
#pragma unroll
        for (int k = 0; k < 8; k++) v[k] = (short)f2bf(W[(kb * 8 + k) * 320 + n]);
        int by = (n * 128 + kb * 16) ^ ((n & 7) << 4);
        *(s8v*)((char*)&wT[mat][0] + by) = v;
    }
    __syncthreads();

    int l = t & 63, wv = t >> 6;
    int g = l >> 4, m = l & 15;
    int wstride = gridDim.x * 128;
    for (int r0 = (blockIdx.x * 8 + wv) * 16; r0 < N; r0 += wstride) {
        // A fragment: lane holds feat[row=r0+m][k=kh*32+g*8+j]
        s8v afr[2];
        {
            long long row = (r0 + m < N) ? (r0 + m) : (N - 1);
#pragma unroll
            for (int kh = 0; kh < 2; kh++) {
                const float* p = feat + row * 64 + kh * 32 + g * 8;
                float4 u0 = *(const float4*)(p);
                float4 u1 = *(const float4*)(p + 4);
                s8v a;
                a[0] = (short)f2bf(u0.x); a[1] = (short)f2bf(u0.y);
                a[2] = (short)f2bf(u0.z); a[3] = (short)f2bf(u0.w);
                a[4] = (short)f2bf(u1.x); a[5] = (short)f2bf(u1.y);
                a[6] = (short)f2bf(u1.z); a[7] = (short)f2bf(u1.w);
                afr[kh] = a;
            }
        }
#pragma unroll
        for (int mat = 0; mat < 2; mat++) {
            const float* bias = mat ? brg : blg;
            ushort* y = mat ? xrbf : xlbf;
            const char* wb = (const char*)&wT[mat][0];
#pragma unroll
            for (int h = 0; h < 5; h++) {
                f4v acc[4];
#pragma unroll
                for (int ct = 0; ct < 4; ct++) acc[ct] = (f4v)0.0f;
#pragma unroll
                for (int ct = 0; ct < 4; ct++) {
                    int n = h * 64 + ct * 16 + m;
                    int b0 = (n * 128 + 0 * 64 + g * 16) ^ ((n & 7) << 4);
                    int b1 = (n * 128 + 1 * 64 + g * 16) ^ ((n & 7) << 4);
                    s8v bf0 = *(const s8v*)(wb + b0);
                    s8v bf1 = *(const s8v*)(wb + b1);
                    acc[ct] = __builtin_amdgcn_mfma_f32_16x16x32_bf16(afr[0], bf0, acc[ct], 0, 0, 0);
                    acc[ct] = __builtin_amdgcn_mfma_f32_16x16x32_bf16(afr[1], bf1, acc[ct], 0, 0, 0);
                }
                float bv[4];
#pragma unroll
                for (int ct = 0; ct < 4; ct++) bv[ct] = bias[h * 64 + ct * 16 + m];
#pragma unroll
                for (int q = 0; q < 4; q++) {
                    int row = r0 + g * 4 + q;
                    if (row < N) {
                        s4v o;
#pragma unroll
                        for (int ct = 0; ct < 4; ct++) o[ct] = (short)f2bf(acc[ct][q] + bv[ct]);
                        *(s4v*)(y + (long long)row * 320 + h * 64 + m * 4) = o;
                    }
                }
            }
        }
    }
}

// ---- K3: fused em-MFMA + logits, 16 rows/wave, head-pipelined, grid-stride -
__global__ __launch_bounds__(512) void k_fused(
    const float* __restrict__ rel, const float* __restrict__ loopat,
    const int* __restrict__ src, const int* __restrict__ dst,
    const ushort* __restrict__ xlbf, const ushort* __restrict__ xrbf,
    const float* __restrict__ Weg, const float* __restrict__ attg,
    const int* __restrict__ posC, const int* __restrict__ roff,
    float* __restrict__ logitsC, int E, int M) {
    __shared__ __align__(16) ushort weT[64 * 320];  // 40 KB
    int t = threadIdx.x;
    // conflict-free staging: one ds_write_b128 per 8 consecutive k
    for (int i = t; i < 2560; i += 512) {  // 320 n x 8 kb
        int n = i >> 3, kb = i & 7;
        s8v v;
#pragma unroll
        for (int k = 0; k < 8; k++) v[k] = (short)f2bf(Weg[(kb * 8 + k) * 320 + n]);
        int by = (n * 128 + kb * 16) ^ ((n & 7) << 4);
        *(s8v*)((char*)weT + by) = v;
    }
    __syncthreads();

    int l = t & 63, wv = t >> 6;
    int g = l >> 4, m = l & 15;
    int wstride = gridDim.x * 128;
    for (int r0 = (blockIdx.x * 8 + wv) * 16; r0 < M; r0 += wstride) {
        // A fragment: lane holds ea[row = r0+m][k = kh*32 + g*8 + j]
        s8v afr[2];
        {
            int row = r0 + m;
            if (row >= M) row = M - 1;
            const float* ap = (row < E) ? (rel + (long long)row * 64)
                                        : (loopat + (long long)(row - E) * 64);
#pragma unroll
            for (int kh = 0; kh < 2; kh++) {
                const float* p = ap + kh * 32 + g * 8;
                float4 u0 = *(const float4*)(p);
                float4 u1 = *(const float4*)(p + 4);
                s8v a;
                a[0] = (short)f2bf(u0.x); a[1] = (short)f2bf(u0.y);
                a[2] = (short)f2bf(u0.z); a[3] = (short)f2bf(u0.w);
                a[4] = (short)f2bf(u1.x); a[5] = (short)f2bf(u1.y);
                a[6] = (short)f2bf(u1.z); a[7] = (short)f2bf(u1.w);
                afr[kh] = a;
            }
        }

        // epilogue rows for this lane: r0 + g*4 + q
        const ushort* xptr[4];
        const ushort* rptr[4];
        int parr[4];
        bool vld[4];
#pragma unroll
        for (int q = 0; q < 4; q++) {
            int row = r0 + g * 4 + q;
            vld[q] = row < M;
            int rr = vld[q] ? row : (M - 1);
            int s, d, p;
            if (rr < E) { s = src[rr]; d = dst[rr]; p = posC[rr]; }
            else        { s = d = rr - E; p = roff[rr - E + 1] - 1; }
            xptr[q] = xlbf + (long long)s * 320 + m * 4;
            rptr[q] = xrbf + (long long)d * 320 + m * 4;
            parr[q] = p;
        }

        // double-buffered per-head gathers (static indices via full unroll)
        s4v xb[2][4], rb[2][4];
        float attb[2][4];
#pragma unroll
        for (int q = 0; q < 4; q++) {
            xb[0][q] = *(const s4v*)(xptr[q]);
            rb[0][q] = *(const s4v*)(rptr[q]);
        }
#pragma unroll
        for (int ct = 0; ct < 4; ct++) attb[0][ct] = attg[ct * 16 + m];

#pragma unroll
        for (int h = 0; h < 5; h++) {
            if (h < 4) {
#pragma unroll
                for (int q = 0; q < 4; q++) {
                    xb[(h + 1) & 1][q] = *(const s4v*)(xptr[q] + (h + 1) * 64);
                    rb[(h + 1) & 1][q] = *(const s4v*)(rptr[q] + (h + 1) * 64);
                }
#pragma unroll
                for (int ct = 0; ct < 4; ct++)
                    attb[(h + 1) & 1][ct] = attg[(h + 1) * 64 + ct * 16 + m];
            }

            f4v acc[4];
#pragma unroll
            for (int ct = 0; ct < 4; ct++) acc[ct] = (f4v)0.0f;
#pragma unroll
            for (int ct = 0; ct < 4; ct++) {
                int n = h * 64 + ct * 16 + m;
                int b0 = (n * 128 + 0 * 64 + g * 16) ^ ((n & 7) << 4);
                int b1 = (n * 128 + 1 * 64 + g * 16) ^ ((n & 7) << 4);
                s8v bf0 = *(const s8v*)((const char*)weT + b0);
                s8v bf1 = *(const s8v*)((const char*)weT + b1);
                acc[ct] = __builtin_amdgcn_mfma_f32_16x16x32_bf16(afr[0], bf0, acc[ct], 0, 0, 0);
                acc[ct] = __builtin_amdgcn_mfma_f32_16x16x32_bf16(afr[1], bf1, acc[ct], 0, 0, 0);
            }

#pragma unroll
            for (int q = 0; q < 4; q++) {
                float sum = 0.f;
#pragma unroll
                for (int ct = 0; ct < 4; ct++) {
                    float v = acc[ct][q] + bf2f((ushort)xb[h & 1][q][ct])
                                         + bf2f((ushort)rb[h & 1][q][ct]);
                    v = v > 0.f ? v : v * NEGS;
                    sum = fmaf(v, attb[h & 1][ct], sum);
                }
                sum += __shfl_xor(sum, 1);
                sum += __shfl_xor(sum, 2);
                sum += __shfl_xor(sum, 4);
                sum += __shfl_xor(sum, 8);
                if (vld[q] && m == 0) logitsC[(long long)parr[q] * 5 + h] = sum;
            }
        }
    }
}

// ---- K4: per-node softmax (no max-shift; logits are small) + conv ----------
__global__ __launch_bounds__(256) void k_agg(const float* __restrict__ logitsC,
                                             const int* __restrict__ srcC,
                                             const int* __restrict__ roff,
                                             const ushort* __restrict__ xlbf,
                                             float* __restrict__ conv, int N) {
    int t = threadIdx.x, ln = t & 63, wv = t >> 6;
    int sub = ln >> 4, m = ln & 15;
    int nw = gridDim.x * 4;
    for (int n = blockIdx.x * 4 + wv; n < N; n += nw) {
        int r0 = roff[n], r1 = roff[n + 1];
        int deg = r1 - r0;  // includes self slot
        float se[5] = {0.f, 0.f, 0.f, 0.f, 0.f};
        for (int j = ln; j < deg; j += 64) {
            long long base = (long long)(r0 + j) * 5;
#pragma unroll
            for (int h = 0; h < 5; h++) se[h] += expf(logitsC[base + h]);
        }
        float dh[5];
#pragma unroll
        for (int h = 0; h < 5; h++) dh[h] = 1.0f / wredsum(se[h]);
        float accv[4] = {0.f, 0.f, 0.f, 0.f};
        for (int jj = sub; jj < deg; jj += 4) {
            int slot = r0 + jj;
            int s = srcC[slot];
            const ushort* xp = xlbf + (long long)s * 320 + m * 4;
            long long lb = (long long)slot * 5;
#pragma unroll
            for (int h = 0; h < 5; h++) {
                float a = expf(logitsC[lb + h]) * dh[h];
                s4v xv = *(const s4v*)(xp + h * 64);
#pragma unroll
                for (int j = 0; j < 4; j++) accv[j] = fmaf(a, bf2f((ushort)xv[j]), accv[j]);
            }
        }
#pragma unroll
        for (int j = 0; j < 4; j++) {
            accv[j] += __shfl_xor(accv[j], 16);
            accv[j] += __shfl_xor(accv[j], 32);
        }
        float v0 = __shfl(accv[0], m);
        float v1 = __shfl(accv[1], m);
        float v2 = __shfl(accv[2], m);
        float v3 = __shfl(accv[3], m);
        float outv = (sub == 0) ? v0 : (sub == 1) ? v1 : (sub == 2) ? v2 : v3;
        conv[(long long)n * 64 + ln] = outv * 0.2f;
    }
}

// ---- K5: residual + LN -> MFMA MLP(64->128->64) -> residual + LN -----------
__global__ __launch_bounds__(512) void k_mlp(const float* __restrict__ feat,
                                             const float* __restrict__ conv,
                                             const float* __restrict__ cbias,
                                             const float* __restrict__ lng,
                                             const float* __restrict__ lnb,
                                             const float* __restrict__ ln1g,
                                             const float* __restrict__ ln1b,
                                             const float* __restrict__ fcwg,
                                             const float* __restrict__ fcb,
                                             const float* __restrict__ fc1wg,
                                             const float* __restrict__ fc1b,
                                             float* __restrict__ out, int N) {
    __shared__ __align__(16) ushort w1T[64 * 128];
    __shared__ __align__(16) ushort w2T[64 * 128];
    __shared__ __align__(16) ushort tls[8][16 * 128];
    __shared__ __align__(16) ushort xnl[8][16 * 64];
    int t = threadIdx.x;
    for (int i = t; i < 8192; i += 512) {
        int k = i >> 7, n = i & 127;
        int by = (n * 128 + k * 2) ^ ((n & 7) << 4);
        w1T[by >> 1] = f2bf(fcwg[i]);
    }
    for (int i = t; i < 8192; i += 512) {
        int k = i >> 6, n = i & 63;
        int by = (n * 256 + k * 2) ^ ((n & 7) << 4);
        w2T[by >> 1] = f2bf(fc1wg[i]);
    }
    __syncthreads();
    int ln = t & 63, wv = t >> 6;
    int g = ln >> 4, m = ln & 15;
    char* tb = (char*)&tls[wv][0];
    char* xb = (char*)&xnl[wv][0];
    float fcbv[8];
#pragma unroll
    for (int ct = 0; ct < 8; ct++) fcbv[ct] = fcb[ct * 16 + m];
    float fc1bv[4], g1v[4], b1v[4];
#pragma unroll
    for (int ct = 0; ct < 4; ct++) {
        fc1bv[ct] = fc1b[ct * 16 + m];
        g1v[ct] = ln1g[ct * 16 + m];
        b1v[ct] = ln1b[ct * 16 + m];
    }
    int nblk = gridDim.x * 8;
    for (int nb0 = (blockIdx.x * 8 + wv) * 16; nb0 < N; nb0 += nblk * 16) {
        int node = nb0 + m;
        long long nd = (node < N) ? node : (N - 1);
        float xv[2][8];
#pragma unroll
        for (int kh = 0; kh < 2; kh++) {
            int c0 = kh * 32 + g * 8;
            const float* fp = feat + nd * 64 + c0;
            const float* cp = conv + nd * 64 + c0;
            float4 f0 = *(const float4*)fp, f1 = *(const float4*)(fp + 4);
            float4 q0 = *(const float4*)cp, q1 = *(const float4*)(cp + 4);
            float4 cb0 = *(const float4*)(cbias + c0), cb1 = *(const float4*)(cbias + c0 + 4);
            xv[kh][0] = f0.x + q0.x + cb0.x; xv[kh][1] = f0.y + q0.y + cb0.y;
            xv[kh][2] = f0.z + q0.z + cb0.z; xv[kh][3] = f0.w + q0.w + cb0.w;
            xv[kh][4] = f1.x + q1.x + cb1.x; xv[kh][5] = f1.y + q1.y + cb1.y;
            xv[kh][6] = f1.z + q1.z + cb1.z; xv[kh][7] = f1.w + q1.w + cb1.w;
        }
        float sm = 0.f;
#pragma unroll
        for (int kh = 0; kh < 2; kh++)
#pragma unroll
            for (int j = 0; j < 8; j++) sm += xv[kh][j];
        sm += __shfl_xor(sm, 16); sm += __shfl_xor(sm, 32);
        float mu = sm * (1.0f / 64.0f);
        float vr = 0.f;
#pragma unroll
        for (int kh = 0; kh < 2; kh++)
#pragma unroll
            for (int j = 0; j < 8; j++) {
                float dv = xv[kh][j] - mu;
                vr += dv * dv;
            }
        vr += __shfl_xor(vr, 16); vr += __shfl_xor(vr, 32);
        float rs = rsqrtf(vr * (1.0f / 64.0f) + LN_EPS);
        s8v af[2];
#pragma unroll
        for (int kh = 0; kh < 2; kh++) {
            int c0 = kh * 32 + g * 8;
            float4 g0 = *(const float4*)(lng + c0), g1 = *(const float4*)(lng + c0 + 4);
            float4 e0 = *(const float4*)(lnb + c0), e1 = *(const float4*)(lnb + c0 + 4);
            float gg[8] = {g0.x, g0.y, g0.z, g0.w, g1.x, g1.y, g1.z, g1.w};
            float bb[8] = {e0.x, e0.y, e0.z, e0.w, e1.x, e1.y, e1.z, e1.w};
#pragma unroll
            for (int j = 0; j < 8; j++)
                af[kh][j] = (short)f2bf((xv[kh][j] - mu) * rs * gg[j] + bb[j]);
            int by = (m * 128 + (kh * 32 + g * 8) * 2) ^ ((m & 7) << 4);
            *(s8v*)(xb + by) = af[kh];
        }
        f4v a1[8];
#pragma unroll
        for (int ct = 0; ct < 8; ct++) a1[ct] = (f4v)0.0f;
#pragma unroll
        for (int ct = 0; ct < 8; ct++) {
            int n1 = ct * 16 + m;
#pragma unroll
            for (int kh = 0; kh < 2; kh++) {
                int by = (n1 * 128 + (kh * 32 + g * 8) * 2) ^ ((n1 & 7) << 4);
                s8v bf = *(const s8v*)((const char*)w1T + by);
                a1[ct] = __builtin_amdgcn_mfma_f32_16x16x32_bf16(af[kh], bf, a1[ct], 0, 0, 0);
            }
        }
#pragma unroll
        for (int ct = 0; ct < 8; ct++)
#pragma unroll
            for (int q = 0; q < 4; q++) {
                int r = g * 4 + q, c = ct * 16 + m;
                int by = (r * 256 + c * 2) ^ ((r & 7) << 4);
                *(ushort*)(tb + by) = f2bf(a1[ct][q] + fcbv[ct]);
            }
        f4v a2[4];
#pragma unroll
        for (int ct = 0; ct < 4; ct++) a2[ct] = (f4v)0.0f;
#pragma unroll
        for (int kh2 = 0; kh2 < 4; kh2++) {
            int by = (m * 256 + (kh2 * 32 + g * 8) * 2) ^ ((m & 7) << 4);
            s8v a2f = *(const s8v*)(tb + by);
#pragma unroll
            for (int ct = 0; ct < 4; ct++) {
                int n2 = ct * 16 + m;
                int by2 = (n2 * 256 + (kh2 * 32 + g * 8) * 2) ^ ((n2 & 7) << 4);
                s8v bf = *(const s8v*)((const char*)w2T + by2);
                a2[ct] = __builtin_amdgcn_mfma_f32_16x16x32_bf16(a2f, bf, a2[ct], 0, 0, 0);
            }
        }
#pragma unroll
        for (int q = 0; q < 4; q++) {
            int r = g * 4 + q;
            float yv[4];
#pragma unroll
            for (int ct = 0; ct < 4; ct++) {
                int by = (r * 128 + (ct * 16 + m) * 2) ^ ((r & 7) << 4);
                yv[ct] = bf2f(*(const ushort*)(xb + by)) + a2[ct][q] + fc1bv[ct];
            }
            float sm2 = (yv[0] + yv[1]) + (yv[2] + yv[3]);
            sm2 += __shfl_xor(sm2, 1); sm2 += __shfl_xor(sm2, 2);
            sm2 += __shfl_xor(sm2, 4); sm2 += __shfl_xor(sm2, 8);
            float mu2 = sm2 * (1.0f / 64.0f);
            float vr2 = 0.f;
#pragma unroll
            for (int ct = 0; ct < 4; ct++) {
                float dv = yv[ct] - mu2;
                vr2 += dv * dv;
            }
            vr2 += __shfl_xor(vr2, 1); vr2 += __shfl_xor(vr2, 2);
            vr2 += __shfl_xor(vr2, 4); vr2 += __shfl_xor(vr2, 8);
            float rs2 = rsqrtf(vr2 * (1.0f / 64.0f) + LN_EPS);
            int rn = nb0 + r;
            if (rn < N) {
#pragma unroll
                for (int ct = 0; ct < 4; ct++)
                    out[(long long)rn * 64 + ct * 16 + m] =
                        (yv[ct] - mu2) * rs2 * g1v[ct] + b1v[ct];
            }
        }
    }
}

// ---- launch ----------------------------------------------------------------
extern "C" void kernel_launch(void* const* d_in, const int* in_sizes, int n_in,
                              void* d_out, int out_size, void* d_ws, size_t ws_size,
                              hipStream_t stream) {
    const float* feat = (const float*)d_in[0];
    const int* ei = (const int*)d_in[1];
    const float* rel = (const float*)d_in[2];
    const float* Wl = (const float*)d_in[3];
    const float* bl = (const float*)d_in[4];
    const float* Wr = (const float*)d_in[5];
    const float* br = (const float*)d_in[6];
    const float* We = (const float*)d_in[7];
    const float* att = (const float*)d_in[8];
    const float* cbias = (const float*)d_in[9];
    const float* lng = (const float*)d_in[10];
    const float* lnb = (const float*)d_in[11];
    const float* ln1g = (const float*)d_in[12];
    const float* ln1b = (const float*)d_in[13];
    const float* fcw = (const float*)d_in[14];
    const float* fcb = (const float*)d_in[15];
    const float* fc1w = (const float*)d_in[16];
    const float* fc1b = (const float*)d_in[17];
    float* out = (float*)d_out;

    int N = in_sizes[0] / 64;
    int E = in_sizes[1] / 2;
    int M = E + N;
    const int* src = ei;
    const int* dst = ei + E;
    int nb = (N + 1023) / 1024;

    char* wsb = (char*)d_ws;
    ushort* xlbf = (ushort*)wsb;            wsb += (size_t)N * 320 * 2;
    ushort* xrbf = (ushort*)wsb;            wsb += (size_t)N * 320 * 2;
    float* loopat = (float*)wsb;            wsb += (size_t)N * 64 * 4;
    float* conv = (float*)wsb;              wsb += (size_t)N * 64 * 4;
    float* logitsC = (float*)wsb;           wsb += (size_t)M * 5 * 4;
    int* cnt = (int*)wsb;                   wsb += (size_t)N * 4;
    int* roff = (int*)wsb;                  wsb += (size_t)(N + 1) * 4;
    int* wpos = (int*)wsb;                  wsb += (size_t)N * 4;
    int* eidC = (int*)wsb;                  wsb += (size_t)M * 4;
    int* srcC = (int*)wsb;                  wsb += (size_t)M * 4;
    int* posC = (int*)wsb;                  wsb += (size_t)E * 4;
    int* bsum = (int*)wsb;                  wsb += 64 * 4;
    int* bpre = (int*)wsb;                  wsb += 64 * 4;

    hipMemsetAsync(cnt, 0, (size_t)N * 4, stream);

    k_hist<<<1024, 256, 0, stream>>>(dst, cnt, E);
    k_scanA<<<nb, 1024, 0, stream>>>(cnt, bsum, N);
    k_scanB<<<1, 64, 0, stream>>>(bsum, bpre, &roff[N], nb);
    k_scanC<<<nb, 1024, 0, stream>>>(cnt, bpre, roff, wpos, N);
    k_scatter<<<1024, 256, 0, stream>>>(src, dst, wpos, eidC, srcC, posC, E);
    k_loopcsr<<<2048, 256, 0, stream>>>(eidC, roff, rel, loopat, srcC, N);
    k_linC<<<(N + 127) / 128, 512, 0, stream>>>(feat, Wl, bl, Wr, br, xlbf, xrbf, N);
    k_fused<<<1024, 512, 0, stream>>>(rel, loopat, src, dst, xlbf, xrbf, We, att,
                                      posC, roff, logitsC, E, M);
    k_agg<<<2048, 256, 0, stream>>>(logitsC, srcC, roff, xlbf, conv, N);
    k_mlp<<<391, 512, 0, stream>>>(feat, conv, cbias, lng, lnb, ln1g, ln1b, fcw, fcb, fc1w, fc1b,
                                   out, N);
}

// Round 8
// 598.578 us; speedup vs baseline: 3.5589x; 1.0772x over previous
//
#include <hip/hip_runtime.h>
#include <hip/hip_bf16.h>
#include <math.h>

#define LN_EPS 1e-5f
#define NEGS 0.2f

typedef short s8v __attribute__((ext_vector_type(8)));
typedef short s4v __attribute__((ext_vector_type(4)));
typedef float f4v __attribute__((ext_vector_type(4)));
typedef unsigned short ushort;

// ---- helpers ---------------------------------------------------------------
__device__ __forceinline__ float wredsum(float v) {
#pragma unroll
    for (int s = 32; s > 0; s >>= 1) v += __shfl_xor(v, s);
    return v;
}
// fp32 -> bf16 (compiler cvt; pairs pack to v_cvt_pk_bf16_f32)
__device__ __forceinline__ ushort f2bf(float x) {
    union { __hip_bfloat16 h; ushort u; } c;
    c.h = __float2bfloat16(x);
    return c.u;
}
__device__ __forceinline__ float bf2f(ushort u) {
    return __uint_as_float(((unsigned int)u) << 16);
}

// ---- K0: histogram of dst --------------------------------------------------
__global__ void k_hist(const int* __restrict__ dst, int* __restrict__ cnt, int E) {
    int idx = blockIdx.x * blockDim.x + threadIdx.x;
    int stride = gridDim.x * blockDim.x;
    for (; idx < E; idx += stride) atomicAdd(&cnt[dst[idx]], 1);
}

// ---- K0b: 3-phase parallel scan of (cnt[i]+1) -------------------------------
__global__ __launch_bounds__(1024) void k_scanA(const int* __restrict__ cnt,
                                                int* __restrict__ bsum, int N) {
    __shared__ int ws[16];
    int tt = threadIdx.x, ln = tt & 63, wv = tt >> 6;
    int i = blockIdx.x * 1024 + tt;
    int v = (i < N) ? (cnt[i] + 1) : 0;
#pragma unroll
    for (int s = 32; s > 0; s >>= 1) v += __shfl_xor(v, s);
    if (ln == 0) ws[wv] = v;
    __syncthreads();
    if (tt == 0) {
        int s = 0;
#pragma unroll
        for (int k = 0; k < 16; k++) s += ws[k];
        bsum[blockIdx.x] = s;
    }
}
// nb <= 64 (N <= 65536)
__global__ __launch_bounds__(64) void k_scanB(const int* __restrict__ bsum,
                                              int* __restrict__ bpre,
                                              int* __restrict__ roffN, int nb) {
    int ln = threadIdx.x;
    int v = (ln < nb) ? bsum[ln] : 0;
    int x = v;
#pragma unroll
    for (int off = 1; off < 64; off <<= 1) {
        int y = __shfl_up(x, off);
        if (ln >= off) x += y;
    }
    if (ln < nb) bpre[ln] = x - v;
    if (ln == 63) *roffN = x;
}
__global__ __launch_bounds__(1024) void k_scanC(const int* __restrict__ cnt,
                                                const int* __restrict__ bpre,
                                                int* __restrict__ roff,
                                                int* __restrict__ wpos, int N) {
    __shared__ int ws[16];
    int tt = threadIdx.x, ln = tt & 63, wv = tt >> 6;
    int i = blockIdx.x * 1024 + tt;
    int v = (i < N) ? (cnt[i] + 1) : 0;
    int x = v;
#pragma unroll
    for (int off = 1; off < 64; off <<= 1) {
        int y = __shfl_up(x, off);
        if (ln >= off) x += y;
    }
    if (ln == 63) ws[wv] = x;
    __syncthreads();
    if (wv == 0) {
        int wsv = (ln < 16) ? ws[ln] : 0;
        int xs = wsv;
#pragma unroll
        for (int off = 1; off < 16; off <<= 1) {
            int y = __shfl_up(xs, off);
            if (ln >= off) xs += y;
        }
        if (ln < 16) ws[ln] = xs - wsv;
    }
    __syncthreads();
    int excl = x - v + ws[wv] + bpre[blockIdx.x];
    if (i < N) { roff[i] = excl; wpos[i] = excl; }
}

// ---- K0c: scatter edges into CSR slots ------------------------------------
__global__ void k_scatter(const int* __restrict__ src, const int* __restrict__ dst,
                          int* __restrict__ wpos, int* __restrict__ eidC,
                          int* __restrict__ srcC, int* __restrict__ posC, int E) {
    int idx = blockIdx.x * blockDim.x + threadIdx.x;
    int stride = gridDim.x * blockDim.x;
    for (; idx < E; idx += stride) {
        int d = dst[idx];
        int p = atomicAdd(&wpos[d], 1);
        eidC[p] = idx;
        srcC[p] = src[idx];
        posC[idx] = p;
    }
}

// ---- K1: per-node loop_attr (mean of incident rel) via CSR -----------------
__global__ __launch_bounds__(256) void k_loopcsr(const int* __restrict__ eidC,
                                                 const int* __restrict__ roff,
                                                 const float* __restrict__ rel,
                                                 float* __restrict__ loopat,
                                                 int* __restrict__ srcC, int N) {
    int t = threadIdx.x, ln = t & 63, wv = t >> 6;
    int nw = gridDim.x * 4;
    for (int n = blockIdx.x * 4 + wv; n < N; n += nw) {
        int r0 = roff[n], r1 = roff[n + 1];
        int deg = r1 - r0 - 1;  // real edges (last slot = self)
        float s0 = 0.f, s1 = 0.f, s2 = 0.f, s3 = 0.f;
        int j = 0;
        for (; j + 4 <= deg; j += 4) {
            int e0 = eidC[r0 + j], e1 = eidC[r0 + j + 1];
            int e2 = eidC[r0 + j + 2], e3 = eidC[r0 + j + 3];
            s0 += rel[(long long)e0 * 64 + ln];
            s1 += rel[(long long)e1 * 64 + ln];
            s2 += rel[(long long)e2 * 64 + ln];
            s3 += rel[(long long)e3 * 64 + ln];
        }
        for (; j < deg; j++) s0 += rel[(long long)eidC[r0 + j] * 64 + ln];
        float s = (s0 + s1) + (s2 + s3);
        loopat[(long long)n * 64 + ln] = s / (float)(deg > 0 ? deg : 1);
        if (ln == 0) srcC[r1 - 1] = n;  // self-loop source
    }
}

// ---- K2: MFMA linear: xl = bf16(feat@Wl+bl), xr = bf16(feat@Wr+br) ---------
// Output layout: permuted within each 64-col head block, pos m*4+ct <-> col ct*16+m.
__global__ __launch_bounds__(512) void k_linC(const float* __restrict__ feat,
                                              const float* __restrict__ Wlg,
                                              const float* __restrict__ blg,
                                              const float* __restrict__ Wrg,
                                              const float* __restrict__ brg,
                                              ushort* __restrict__ xlbf,
                                              ushort* __restrict__ xrbf, int N) {
    __shared__ __align__(16) ushort wT[2][64 * 320];  // 80 KB, byte=n*128+k*2 ^ ((n&7)<<4)
    int t = threadIdx.x;
    for (int i = t; i < 5120; i += 512) {  // 2 mats x 320 n x 8 kb
        int mat = i >= 2560;
        int j = mat ? (i - 2560) : i;
        int n = j >> 3, kb = j & 7;
        const float* W = mat ? Wrg : Wlg;
        s8v v;
#pragma unroll
        for (int k = 0; k < 8; k++) v[k] = (short)f2bf(W[(kb * 8 + k) * 320 + n]);
        int by = (n * 128 + kb * 16) ^ ((n & 7) << 4);
        *(s8v*)((char*)&wT[mat][0] + by) = v;
    }
    __syncthreads();

    int l = t & 63, wv = t >> 6;
    int g = l >> 4, m = l & 15;
    int wstride = gridDim.x * 128;
    for (int r0 = (blockIdx.x * 8 + wv) * 16; r0 < N; r0 += wstride) {
        // A fragment: lane holds feat[row=r0+m][k=kh*32+g*8+j]
        s8v afr[2];
        {
            long long row = (r0 + m < N) ? (r0 + m) : (N - 1);
#pragma unroll
            for (int kh = 0; kh < 2; kh++) {
                const float* p = feat + row * 64 + kh * 32 + g * 8;
                float4 u0 = *(const float4*)(p);
                float4 u1 = *(const float4*)(p + 4);
                s8v a;
                a[0] = (short)f2bf(u0.x); a[1] = (short)f2bf(u0.y);
                a[2] = (short)f2bf(u0.z); a[3] = (short)f2bf(u0.w);
                a[4] = (short)f2bf(u1.x); a[5] = (short)f2bf(u1.y);
                a[6] = (short)f2bf(u1.z); a[7] = (short)f2bf(u1.w);
                afr[kh] = a;
            }
        }
#pragma unroll
        for (int mat = 0; mat < 2; mat++) {
            const float* bias = mat ? brg : blg;
            ushort* y = mat ? xrbf : xlbf;
            const char* wb = (const char*)&wT[mat][0];
#pragma unroll
            for (int h = 0; h < 5; h++) {
                f4v acc[4];
#pragma unroll
                for (int ct = 0; ct < 4; ct++) acc[ct] = (f4v)0.0f;
#pragma unroll
                for (int ct = 0; ct < 4; ct++) {
                    int n = h * 64 + ct * 16 + m;
                    int b0 = (n * 128 + 0 * 64 + g * 16) ^ ((n & 7) << 4);
                    int b1 = (n * 128 + 1 * 64 + g * 16) ^ ((n & 7) << 4);
                    s8v bf0 = *(const s8v*)(wb + b0);
                    s8v bf1 = *(const s8v*)(wb + b1);
                    acc[ct] = __builtin_amdgcn_mfma_f32_16x16x32_bf16(afr[0], bf0, acc[ct], 0, 0, 0);
                    acc[ct] = __builtin_amdgcn_mfma_f32_16x16x32_bf16(afr[1], bf1, acc[ct], 0, 0, 0);
                }
                float bv[4];
#pragma unroll
                for (int ct = 0; ct < 4; ct++) bv[ct] = bias[h * 64 + ct * 16 + m];
#pragma unroll
                for (int q = 0; q < 4; q++) {
                    int row = r0 + g * 4 + q;
                    if (row < N) {
                        s4v o;
#pragma unroll
                        for (int ct = 0; ct < 4; ct++) o[ct] = (short)f2bf(acc[ct][q] + bv[ct]);
                        *(s4v*)(y + (long long)row * 320 + h * 64 + m * 4) = o;
                    }
                }
            }
        }
    }
}

// ---- K3: fused em-MFMA + logits, 16 rows/wave, head-pipelined, EXACT grid --
// (no grid-stride loop: loop version ballooned to 128 VGPR / 23% occ — R7)
__global__ __launch_bounds__(512) void k_fused(
    const float* __restrict__ rel, const float* __restrict__ loopat,
    const int* __restrict__ src, const int* __restrict__ dst,
    const ushort* __restrict__ xlbf, const ushort* __restrict__ xrbf,
    const float* __restrict__ Weg, const float* __restrict__ attg,
    const int* __restrict__ posC, const int* __restrict__ roff,
    float* __restrict__ logitsC, int E, int M) {
    __shared__ __align__(16) ushort weT[64 * 320];  // 40 KB
    int t = threadIdx.x;
    // conflict-free staging: one ds_write_b128 per 8 consecutive k
    for (int i = t; i < 2560; i += 512) {  // 320 n x 8 kb
        int n = i >> 3, kb = i & 7;
        s8v v;
#pragma unroll
        for (int k = 0; k < 8; k++) v[k] = (short)f2bf(Weg[(kb * 8 + k) * 320 + n]);
        int by = (n * 128 + kb * 16) ^ ((n & 7) << 4);
        *(s8v*)((char*)weT + by) = v;
    }
    __syncthreads();

    int l = t & 63, wv = t >> 6;
    int g = l >> 4, m = l & 15;
    int r0 = (blockIdx.x * 8 + wv) * 16;
    if (r0 >= M) return;

    // A fragment: lane holds ea[row = r0+m][k = kh*32 + g*8 + j]
    s8v afr[2];
    {
        int row = r0 + m;
        if (row >= M) row = M - 1;
        const float* ap = (row < E) ? (rel + (long long)row * 64)
                                    : (loopat + (long long)(row - E) * 64);
#pragma unroll
        for (int kh = 0; kh < 2; kh++) {
            const float* p = ap + kh * 32 + g * 8;
            float4 u0 = *(const float4*)(p);
            float4 u1 = *(const float4*)(p + 4);
            s8v a;
            a[0] = (short)f2bf(u0.x); a[1] = (short)f2bf(u0.y);
            a[2] = (short)f2bf(u0.z); a[3] = (short)f2bf(u0.w);
            a[4] = (short)f2bf(u1.x); a[5] = (short)f2bf(u1.y);
            a[6] = (short)f2bf(u1.z); a[7] = (short)f2bf(u1.w);
            afr[kh] = a;
        }
    }

    // epilogue rows for this lane: r0 + g*4 + q
    const ushort* xptr[4];
    const ushort* rptr[4];
    int parr[4];
    bool vld[4];
#pragma unroll
    for (int q = 0; q < 4; q++) {
        int row = r0 + g * 4 + q;
        vld[q] = row < M;
        int rr = vld[q] ? row : (M - 1);
        int s, d, p;
        if (rr < E) { s = src[rr]; d = dst[rr]; p = posC[rr]; }
        else        { s = d = rr - E; p = roff[rr - E + 1] - 1; }
        xptr[q] = xlbf + (long long)s * 320 + m * 4;
        rptr[q] = xrbf + (long long)d * 320 + m * 4;
        parr[q] = p;
    }

    // double-buffered per-head gathers (static indices via full unroll)
    s4v xb[2][4], rb[2][4];
    float attb[2][4];
#pragma unroll
    for (int q = 0; q < 4; q++) {
        xb[0][q] = *(const s4v*)(xptr[q]);
        rb[0][q] = *(const s4v*)(rptr[q]);
    }
#pragma unroll
    for (int ct = 0; ct < 4; ct++) attb[0][ct] = attg[ct * 16 + m];

#pragma unroll
    for (int h = 0; h < 5; h++) {
        if (h < 4) {
#pragma unroll
            for (int q = 0; q < 4; q++) {
                xb[(h + 1) & 1][q] = *(const s4v*)(xptr[q] + (h + 1) * 64);
                rb[(h + 1) & 1][q] = *(const s4v*)(rptr[q] + (h + 1) * 64);
            }
#pragma unroll
            for (int ct = 0; ct < 4; ct++)
                attb[(h + 1) & 1][ct] = attg[(h + 1) * 64 + ct * 16 + m];
        }

        f4v acc[4];
#pragma unroll
        for (int ct = 0; ct < 4; ct++) acc[ct] = (f4v)0.0f;
#pragma unroll
        for (int ct = 0; ct < 4; ct++) {
            int n = h * 64 + ct * 16 + m;
            int b0 = (n * 128 + 0 * 64 + g * 16) ^ ((n & 7) << 4);
            int b1 = (n * 128 + 1 * 64 + g * 16) ^ ((n & 7) << 4);
            s8v bf0 = *(const s8v*)((const char*)weT + b0);
            s8v bf1 = *(const s8v*)((const char*)weT + b1);
            acc[ct] = __builtin_amdgcn_mfma_f32_16x16x32_bf16(afr[0], bf0, acc[ct], 0, 0, 0);
            acc[ct] = __builtin_amdgcn_mfma_f32_16x16x32_bf16(afr[1], bf1, acc[ct], 0, 0, 0);
        }

#pragma unroll
        for (int q = 0; q < 4; q++) {
            float sum = 0.f;
#pragma unroll
            for (int ct = 0; ct < 4; ct++) {
                float v = acc[ct][q] + bf2f((ushort)xb[h & 1][q][ct])
                                     + bf2f((ushort)rb[h & 1][q][ct]);
                v = v > 0.f ? v : v * NEGS;
                sum = fmaf(v, attb[h & 1][ct], sum);
            }
            sum += __shfl_xor(sum, 1);
            sum += __shfl_xor(sum, 2);
            sum += __shfl_xor(sum, 4);
            sum += __shfl_xor(sum, 8);
            if (vld[q] && m == 0) logitsC[(long long)parr[q] * 5 + h] = sum;
        }
    }
}

// ---- K4: per-node softmax (no max-shift; logits are small) + conv ----------
__global__ __launch_bounds__(256) void k_agg(const float* __restrict__ logitsC,
                                             const int* __restrict__ srcC,
                                             const int* __restrict__ roff,
                                             const ushort* __restrict__ xlbf,
                                             float* __restrict__ conv, int N) {
    int t = threadIdx.x, ln = t & 63, wv = t >> 6;
    int sub = ln >> 4, m = ln & 15;
    int nw = gridDim.x * 4;
    for (int n = blockIdx.x * 4 + wv; n < N; n += nw) {
        int r0 = roff[n], r1 = roff[n + 1];
        int deg = r1 - r0;  // includes self slot
        float se[5] = {0.f, 0.f, 0.f, 0.f, 0.f};
        for (int j = ln; j < deg; j += 64) {
            long long base = (long long)(r0 + j) * 5;
#pragma unroll
            for (int h = 0; h < 5; h++) se[h] += expf(logitsC[base + h]);
        }
        float dh[5];
#pragma unroll
        for (int h = 0; h < 5; h++) dh[h] = 1.0f / wredsum(se[h]);
        float accv[4] = {0.f, 0.f, 0.f, 0.f};
        for (int jj = sub; jj < deg; jj += 4) {
            int slot = r0 + jj;
            int s = srcC[slot];
            const ushort* xp = xlbf + (long long)s * 320 + m * 4;
            long long lb = (long long)slot * 5;
#pragma unroll
            for (int h = 0; h < 5; h++) {
                float a = expf(logitsC[lb + h]) * dh[h];
                s4v xv = *(const s4v*)(xp + h * 64);
#pragma unroll
                for (int j = 0; j < 4; j++) accv[j] = fmaf(a, bf2f((ushort)xv[j]), accv[j]);
            }
        }
#pragma unroll
        for (int j = 0; j < 4; j++) {
            accv[j] += __shfl_xor(accv[j], 16);
            accv[j] += __shfl_xor(accv[j], 32);
        }
        float v0 = __shfl(accv[0], m);
        float v1 = __shfl(accv[1], m);
        float v2 = __shfl(accv[2], m);
        float v3 = __shfl(accv[3], m);
        float outv = (sub == 0) ? v0 : (sub == 1) ? v1 : (sub == 2) ? v2 : v3;
        conv[(long long)n * 64 + ln] = outv * 0.2f;
    }
}

// ---- K5: residual + LN -> MFMA MLP(64->128->64) -> residual + LN -----------
__global__ __launch_bounds__(512) void k_mlp(const float* __restrict__ feat,
                                             const float* __restrict__ conv,
                                             const float* __restrict__ cbias,
                                             const float* __restrict__ lng,
                                             const float* __restrict__ lnb,
                                             const float* __restrict__ ln1g,
                                             const float* __restrict__ ln1b,
                                             const float* __restrict__ fcwg,
                                             const float* __restrict__ fcb,
                                             const float* __restrict__ fc1wg,
                                             const float* __restrict__ fc1b,
                                             float* __restrict__ out, int N) {
    __shared__ __align__(16) ushort w1T[64 * 128];
    __shared__ __align__(16) ushort w2T[64 * 128];
    __shared__ __align__(16) ushort tls[8][16 * 128];
    __shared__ __align__(16) ushort xnl[8][16 * 64];
    int t = threadIdx.x;
    for (int i = t; i < 8192; i += 512) {
        int k = i >> 7, n = i & 127;
        int by = (n * 128 + k * 2) ^ ((n & 7) << 4);
        w1T[by >> 1] = f2bf(fcwg[i]);
    }
    for (int i = t; i < 8192; i += 512) {
        int k = i >> 6, n = i & 63;
        int by = (n * 256 + k * 2) ^ ((n & 7) << 4);
        w2T[by >> 1] = f2bf(fc1wg[i]);
    }
    __syncthreads();
    int ln = t & 63, wv = t >> 6;
    int g = ln >> 4, m = ln & 15;
    char* tb = (char*)&tls[wv][0];
    char* xb = (char*)&xnl[wv][0];
    float fcbv[8];
#pragma unroll
    for (int ct = 0; ct < 8; ct++) fcbv[ct] = fcb[ct * 16 + m];
    float fc1bv[4], g1v[4], b1v[4];
#pragma unroll
    for (int ct = 0; ct < 4; ct++) {
        fc1bv[ct] = fc1b[ct * 16 + m];
        g1v[ct] = ln1g[ct * 16 + m];
        b1v[ct] = ln1b[ct * 16 + m];
    }
    int nblk = gridDim.x * 8;
    for (int nb0 = (blockIdx.x * 8 + wv) * 16; nb0 < N; nb0 += nblk * 16) {
        int node = nb0 + m;
        long long nd = (node < N) ? node : (N - 1);
        float xv[2][8];
#pragma unroll
        for (int kh = 0; kh < 2; kh++) {
            int c0 = kh * 32 + g * 8;
            const float* fp = feat + nd * 64 + c0;
            const float* cp = conv + nd * 64 + c0;
            float4 f0 = *(const float4*)fp, f1 = *(const float4*)(fp + 4);
            float4 q0 = *(const float4*)cp, q1 = *(const float4*)(cp + 4);
            float4 cb0 = *(const float4*)(cbias + c0), cb1 = *(const float4*)(cbias + c0 + 4);
            xv[kh][0] = f0.x + q0.x + cb0.x; xv[kh][1] = f0.y + q0.y + cb0.y;
            xv[kh][2] = f0.z + q0.z + cb0.z; xv[kh][3] = f0.w + q0.w + cb0.w;
            xv[kh][4] = f1.x + q1.x + cb1.x; xv[kh][5] = f1.y + q1.y + cb1.y;
            xv[kh][6] = f1.z + q1.z + cb1.z; xv[kh][7] = f1.w + q1.w + cb1.w;
        }
        float sm = 0.f;
#pragma unroll
        for (int kh = 0; kh < 2; kh++)
#pragma unroll
            for (int j = 0; j < 8; j++) sm += xv[kh][j];
        sm += __shfl_xor(sm, 16); sm += __shfl_xor(sm, 32);
        float mu = sm * (1.0f / 64.0f);
        float vr = 0.f;
#pragma unroll
        for (int kh = 0; kh < 2; kh++)
#pragma unroll
            for (int j = 0; j < 8; j++) {
                float dv = xv[kh][j] - mu;
                vr += dv * dv;
            }
        vr += __shfl_xor(vr, 16); vr += __shfl_xor(vr, 32);
        float rs = rsqrtf(vr * (1.0f / 64.0f) + LN_EPS);
        s8v af[2];
#pragma unroll
        for (int kh = 0; kh < 2; kh++) {
            int c0 = kh * 32 + g * 8;
            float4 g0 = *(const float4*)(lng + c0), g1 = *(const float4*)(lng + c0 + 4);
            float4 e0 = *(const float4*)(lnb + c0), e1 = *(const float4*)(lnb + c0 + 4);
            float gg[8] = {g0.x, g0.y, g0.z, g0.w, g1.x, g1.y, g1.z, g1.w};
            float bb[8] = {e0.x, e0.y, e0.z, e0.w, e1.x, e1.y, e1.z, e1.w};
#pragma unroll
            for (int j = 0; j < 8; j++)
                af[kh][j] = (short)f2bf((xv[kh][j] - mu) * rs * gg[j] + bb[j]);
            int by = (m * 128 + (kh * 32 + g * 8) * 2) ^ ((m & 7) << 4);
            *(s8v*)(xb + by) = af[kh];
        }
        f4v a1[8];
#pragma unroll
        for (int ct = 0; ct < 8; ct++) a1[ct] = (f4v)0.0f;
#pragma unroll
        for (int ct = 0; ct < 8; ct++) {
            int n1 = ct * 16 + m;
#pragma unroll
            for (int kh = 0; kh < 2; kh++) {
                int by = (n1 * 128 + (kh * 32 + g * 8) * 2) ^ ((n1 & 7) << 4);
                s8v bf = *(const s8v*)((const char*)w1T + by);
                a1[ct] = __builtin_amdgcn_mfma_f32_16x16x32_bf16(af[kh], bf, a1[ct], 0, 0, 0);
            }
        }
#pragma unroll
        for (int ct = 0; ct < 8; ct++)
#pragma unroll
            for (int q = 0; q < 4; q++) {
                int r = g * 4 + q, c = ct * 16 + m;
                int by = (r * 256 + c * 2) ^ ((r & 7) << 4);
                *(ushort*)(tb + by) = f2bf(a1[ct][q] + fcbv[ct]);
            }
        f4v a2[4];
#pragma unroll
        for (int ct = 0; ct < 4; ct++) a2[ct] = (f4v)0.0f;
#pragma unroll
        for (int kh2 = 0; kh2 < 4; kh2++) {
            int by = (m * 256 + (kh2 * 32 + g * 8) * 2) ^ ((m & 7) << 4);
            s8v a2f = *(const s8v*)(tb + by);
#pragma unroll
            for (int ct = 0; ct < 4; ct++) {
                int n2 = ct * 16 + m;
                int by2 = (n2 * 256 + (kh2 * 32 + g * 8) * 2) ^ ((n2 & 7) << 4);
                s8v bf = *(const s8v*)((const char*)w2T + by2);
                a2[ct] = __builtin_amdgcn_mfma_f32_16x16x32_bf16(a2f, bf, a2[ct], 0, 0, 0);
            }
        }
#pragma unroll
        for (int q = 0; q < 4; q++) {
            int r = g * 4 + q;
            float yv[4];
#pragma unroll
            for (int ct = 0; ct < 4; ct++) {
                int by = (r * 128 + (ct * 16 + m) * 2) ^ ((r & 7) << 4);
                yv[ct] = bf2f(*(const ushort*)(xb + by)) + a2[ct][q] + fc1bv[ct];
            }
            float sm2 = (yv[0] + yv[1]) + (yv[2] + yv[3]);
            sm2 += __shfl_xor(sm2, 1); sm2 += __shfl_xor(sm2, 2);
            sm2 += __shfl_xor(sm2, 4); sm2 += __shfl_xor(sm2, 8);
            float mu2 = sm2 * (1.0f / 64.0f);
            float vr2 = 0.f;
#pragma unroll
            for (int ct = 0; ct < 4; ct++) {
                float dv = yv[ct] - mu2;
                vr2 += dv * dv;
            }
            vr2 += __shfl_xor(vr2, 1); vr2 += __shfl_xor(vr2, 2);
            vr2 += __shfl_xor(vr2, 4); vr2 += __shfl_xor(vr2, 8);
            float rs2 = rsqrtf(vr2 * (1.0f / 64.0f) + LN_EPS);
            int rn = nb0 + r;
            if (rn < N) {
#pragma unroll
                for (int ct = 0; ct < 4; ct++)
                    out[(long long)rn * 64 + ct * 16 + m] =
                        (yv[ct] - mu2) * rs2 * g1v[ct] + b1v[ct];
            }
        }
    }
}

// ---- launch ----------------------------------------------------------------
extern "C" void kernel_launch(void* const* d_in, const int* in_sizes, int n_in,
                              void* d_out, int out_size, void* d_ws, size_t ws_size,
                              hipStream_t stream) {
    const float* feat = (const float*)d_in[0];
    const int* ei = (const int*)d_in[1];
    const float* rel = (const float*)d_in[2];
    const float* Wl = (const float*)d_in[3];
    const float* bl = (const float*)d_in[4];
    const float* Wr = (const float*)d_in[5];
    const float* br = (const float*)d_in[6];
    const float* We = (const float*)d_in[7];
    const float* att = (const float*)d_in[8];
    const float* cbias = (const float*)d_in[9];
    const float* lng = (const float*)d_in[10];
    const float* lnb = (const float*)d_in[11];
    const float* ln1g = (const float*)d_in[12];
    const float* ln1b = (const float*)d_in[13];
    const float* fcw = (const float*)d_in[14];
    const float* fcb = (const float*)d_in[15];
    const float* fc1w = (const float*)d_in[16];
    const float* fc1b = (const float*)d_in[17];
    float* out = (float*)d_out;

    int N = in_sizes[0] / 64;
    int E = in_sizes[1] / 2;
    int M = E + N;
    const int* src = ei;
    const int* dst = ei + E;
    int nb = (N + 1023) / 1024;

    char* wsb = (char*)d_ws;
    ushort* xlbf = (ushort*)wsb;            wsb += (size_t)N * 320 * 2;
    ushort* xrbf = (ushort*)wsb;            wsb += (size_t)N * 320 * 2;
    float* loopat = (float*)wsb;            wsb += (size_t)N * 64 * 4;
    float* conv = (float*)wsb;              wsb += (size_t)N * 64 * 4;
    float* logitsC = (float*)wsb;           wsb += (size_t)M * 5 * 4;
    int* cnt = (int*)wsb;                   wsb += (size_t)N * 4;
    int* roff = (int*)wsb;                  wsb += (size_t)(N + 1) * 4;
    int* wpos = (int*)wsb;                  wsb += (size_t)N * 4;
    int* eidC = (int*)wsb;                  wsb += (size_t)M * 4;
    int* srcC = (int*)wsb;                  wsb += (size_t)M * 4;
    int* posC = (int*)wsb;                  wsb += (size_t)E * 4;
    int* bsum = (int*)wsb;                  wsb += 64 * 4;
    int* bpre = (int*)wsb;                  wsb += 64 * 4;

    hipMemsetAsync(cnt, 0, (size_t)N * 4, stream);

    k_hist<<<1024, 256, 0, stream>>>(dst, cnt, E);
    k_scanA<<<nb, 1024, 0, stream>>>(cnt, bsum, N);
    k_scanB<<<1, 64, 0, stream>>>(bsum, bpre, &roff[N], nb);
    k_scanC<<<nb, 1024, 0, stream>>>(cnt, bpre, roff, wpos, N);
    k_scatter<<<1024, 256, 0, stream>>>(src, dst, wpos, eidC, srcC, posC, E);
    k_loopcsr<<<2048, 256, 0, stream>>>(eidC, roff, rel, loopat, srcC, N);
    k_linC<<<(N + 127) / 128, 512, 0, stream>>>(feat, Wl, bl, Wr, br, xlbf, xrbf, N);
    k_fused<<<(M + 127) / 128, 512, 0, stream>>>(rel, loopat, src, dst, xlbf, xrbf, We, att,
                                                 posC, roff, logitsC, E, M);
    k_agg<<<2048, 256, 0, stream>>>(logitsC, srcC, roff, xlbf, conv, N);
    k_mlp<<<391, 512, 0, stream>>>(feat, conv, cbias, lng, lnb, ln1g, ln1b, fcw, fcb, fc1w, fc1b,
                                   out, N);
}